// Round 10
// baseline (595.104 us; speedup 1.0000x reference)
//
#include <hip/hip_runtime.h>
#include <cstdio>

typedef unsigned short u16;
typedef __bf16 bf16x8 __attribute__((ext_vector_type(8)));
typedef float f32x4 __attribute__((ext_vector_type(4)));
typedef unsigned short us4 __attribute__((ext_vector_type(4)));
typedef unsigned short us8 __attribute__((ext_vector_type(8)));

__device__ __forceinline__ u16 f2bf(float f) {
    union { float f; unsigned u; } x; x.f = f;
    unsigned u = x.u + 0x7fffu + ((x.u >> 16) & 1u);   // RNE
    return (u16)(u >> 16);
}
__device__ __forceinline__ float bf2f(u16 u) {
    union { unsigned u; float f; } x; x.u = ((unsigned)u) << 16;
    return x.f;
}

// ---------------------------------------------------------------------------
// NT GEMM: C[M,N] = A[M,K] * B[N,K]^T, bf16 in, fp32 accumulate.
// 128x128 tile, BK=32, 256 threads (4 waves 2x2, 64x64 per wave) — the m97
// occupancy regime: 48 KiB LDS (3 bufs) + ~140 VGPR -> ~3 blocks/CU, 12
// waves/CU; cross-block wave overlap fills barrier/latency stalls (m114).
// Counted vmcnt 3-deep: stage(T+2) issued at top of T; s_waitcnt vmcnt(8)
// (= 2 tiles x 4 loads in flight) guarantees tile T's loads landed. No
// mid-loop vmcnt(0).
// Hazards (R6-verified loop):
//   RAW global->LDS: own-wave vmcnt(8) + lead barrier -> all waves' tile-T
//     loads landed before any ds_read of T.
//   WAR: buf b=T%3 next overwritten by stage(T+3), issued at top of T+1,
//     after T's trailing barrier which follows all reads of buf b.
//   RAW LDS->MFMA: compiler-inserted fine-grained lgkmcnt (plain C++ loads).
// EMIT_VT (G2): epilogue also writes V^T[b][n][s] from registers.
// grid: (N/128, M/128, batch) flattened; nwg % 8 == 0 for the XCD remap.
// ---------------------------------------------------------------------------
template<int TAG, bool HAS_BIAS, bool HAS_RESID, bool OUT_BF16, bool EMIT_VT>
__global__ __launch_bounds__(256)
void gemm_nt(const u16* __restrict__ A, const u16* __restrict__ Bm,
             void* __restrict__ Cm, const float* __restrict__ bias,
             const float* __restrict__ resid, u16* __restrict__ vt,
             int K, int lda, int ldb, int ldc,
             long sA, long sB, long sC, float scale)
{
    __shared__ __align__(16) u16 lA[3][128 * 32];   // 3 x 8 KiB
    __shared__ __align__(16) u16 lB[3][128 * 32];   // 3 x 8 KiB, total 48 KiB

    const int tid = threadIdx.x;

    // ---- bijective XCD chunking over the flattened 3D grid (nwg%8==0) ----
    const int gx = gridDim.x, gy = gridDim.y;
    int flat = ((int)blockIdx.z * gy + blockIdx.y) * gx + blockIdx.x;
    const int nwg = gx * gy * (int)gridDim.z;
    const int q = nwg >> 3;
    flat = (flat & 7) * q + (flat >> 3);
    const int bx = flat % gx;
    const int t2 = flat / gx;
    const int by = t2 % gy;
    const long bz = t2 / gy;

    A  += bz * sA;
    Bm += bz * sB;
    const long cbase = bz * sC;
    const int m0 = by * 128;
    const int n0 = bx * 128;

    const int lane = tid & 63;
    const int w  = tid >> 6;                  // wave 0..3
    const int wr = w >> 1, wc = w & 1;        // 2x2 wave grid, 64x64 per wave
    const int fr = lane & 15;                 // A row / B col within fragment
    const int kg = lane >> 4;                 // k-group (0..3) of 8

    // staging: per K-step 8 KiB per operand = 512 16B-chunks; 256 thr x 2
    // -> 4 global_load_lds per thread per stage
    auto stage = [&](int b, int kt) {
#pragma unroll
        for (int h = 0; h < 2; ++h) {
            const int c = h * 256 + tid;           // chunk 0..511
            const int row = c >> 2, seg = c & 3;   // 4 x 16B per 64B row
            const u16* sAp = A + (long)(m0 + row) * lda + (kt * 32 + seg * 8);
            __builtin_amdgcn_global_load_lds(
                (const __attribute__((address_space(1))) void*)sAp,
                (__attribute__((address_space(3))) void*)(&lA[b][c * 8]), 16, 0, 0);
            const u16* sBp = Bm + (long)(n0 + row) * ldb + (kt * 32 + seg * 8);
            __builtin_amdgcn_global_load_lds(
                (const __attribute__((address_space(1))) void*)sBp,
                (__attribute__((address_space(3))) void*)(&lB[b][c * 8]), 16, 0, 0);
        }
    };

    f32x4 acc[4][4] = {};

    const int nk = K >> 5;                 // K multiples of 32, nk >= 24 here
    stage(0, 0);
    stage(1, 1);
    for (int kt = 0; kt < nk; ++kt) {
        const int b = kt % 3;
        if (kt + 2 < nk) {
            stage((kt + 2) % 3, kt + 2);   // keep 2 tiles in flight
            asm volatile("s_waitcnt vmcnt(8)" ::: "memory");  // tile kt landed
        } else if (kt + 1 < nk) {
            asm volatile("s_waitcnt vmcnt(4)" ::: "memory");
        } else {
            asm volatile("s_waitcnt vmcnt(0)" ::: "memory");
        }
        __builtin_amdgcn_s_barrier();      // all waves' tile-kt loads visible
        asm volatile("" ::: "memory");

        bf16x8 af[4], bfv[4];
#pragma unroll
        for (int mf = 0; mf < 4; ++mf)
            af[mf] = *(const bf16x8*)&lA[b][(wr * 64 + mf * 16 + fr) * 32 + kg * 8];
#pragma unroll
        for (int nf = 0; nf < 4; ++nf)
            bfv[nf] = *(const bf16x8*)&lB[b][(wc * 64 + nf * 16 + fr) * 32 + kg * 8];

        __builtin_amdgcn_s_setprio(1);
#pragma unroll
        for (int mf = 0; mf < 4; ++mf)
#pragma unroll
            for (int nf = 0; nf < 4; ++nf)
                acc[mf][nf] = __builtin_amdgcn_mfma_f32_16x16x32_bf16(
                    af[mf], bfv[nf], acc[mf][nf], 0, 0, 0);
        __builtin_amdgcn_s_setprio(0);

        asm volatile("" ::: "memory");
        __builtin_amdgcn_s_barrier();      // reads of buf b done before
        asm volatile("" ::: "memory");     // stage(kt+3) overwrites it
    }

    // epilogue: C/D layout col=lane&15, row=(lane>>4)*4+reg  [m89-verified]
    const int orow = m0 + wr * 64 + kg * 4;
    const int ocol = n0 + wc * 64 + fr;
#pragma unroll
    for (int mf = 0; mf < 4; ++mf) {
        const int mbase = orow + mf * 16;     // 4 consecutive rows mbase..+3
#pragma unroll
        for (int nf = 0; nf < 4; ++nf) {
            const int n = ocol + nf * 16;
            float v4[4];
#pragma unroll
            for (int r = 0; r < 4; ++r) {
                const int m = mbase + r;
                float v = acc[mf][nf][r] * scale;
                if (HAS_BIAS)  v += bias[n];
                if (HAS_RESID) v += resid[cbase + (long)m * ldc + n];
                v4[r] = v;
                if (OUT_BF16)  ((u16*)Cm)[cbase + (long)m * ldc + n] = f2bf(v);
                else           ((float*)Cm)[cbase + (long)m * ldc + n] = v;
            }
            if (EMIT_VT) {
                // rows m = b*2048 + s; write Vt[b][n][s..s+3] (batch S=2048)
                const long b_ = mbase >> 11;
                const int  s  = mbase & 2047;
                us4 o;
#pragma unroll
                for (int r = 0; r < 4; ++r) o[r] = f2bf(v4[r]);
                *(us4*)(vt + (b_ * 1024 + n) * 2048 + s) = o;
            }
        }
    }
}

// ---------------------------------------------------------------------------
// LayerNorm over D=1024, one block (256 thr) per row.
// ---------------------------------------------------------------------------
template<bool IN_BF16, bool OUT_BF16>
__global__ __launch_bounds__(256)
void ln1024(const void* in, const float* __restrict__ g,
            const float* __restrict__ beta, void* out)
{
    const long row = blockIdx.x;
    const int tid = threadIdx.x;
    float x0, x1, x2, x3;
    if (IN_BF16) {
        const us4 v = ((const us4*)in)[row * 256 + tid];
        x0 = bf2f(v[0]); x1 = bf2f(v[1]); x2 = bf2f(v[2]); x3 = bf2f(v[3]);
    } else {
        const float4 v = ((const float4*)in)[row * 256 + tid];
        x0 = v.x; x1 = v.y; x2 = v.z; x3 = v.w;
    }
    float s  = x0 + x1 + x2 + x3;
    float s2 = x0 * x0 + x1 * x1 + x2 * x2 + x3 * x3;
#pragma unroll
    for (int off = 32; off > 0; off >>= 1) {
        s  += __shfl_xor(s, off);
        s2 += __shfl_xor(s2, off);
    }
    __shared__ float rs[4], rq[4];
    if ((tid & 63) == 0) { rs[tid >> 6] = s; rq[tid >> 6] = s2; }
    __syncthreads();
    const float S  = rs[0] + rs[1] + rs[2] + rs[3];
    const float S2 = rq[0] + rq[1] + rq[2] + rq[3];
    const float mu = S * (1.0f / 1024.0f);
    const float var = S2 * (1.0f / 1024.0f) - mu * mu;
    const float rstd = rsqrtf(var + 1e-5f);
    const float4 gg = ((const float4*)g)[tid];
    const float4 bb = ((const float4*)beta)[tid];
    const float y0 = (x0 - mu) * rstd * gg.x + bb.x;
    const float y1 = (x1 - mu) * rstd * gg.y + bb.y;
    const float y2 = (x2 - mu) * rstd * gg.z + bb.z;
    const float y3 = (x3 - mu) * rstd * gg.w + bb.w;
    if (OUT_BF16) {
        us4 o; o[0] = f2bf(y0); o[1] = f2bf(y1); o[2] = f2bf(y2); o[3] = f2bf(y3);
        ((us4*)out)[row * 256 + tid] = o;
    } else {
        float4 o; o.x = y0; o.y = y1; o.z = y2; o.w = y3;
        ((float4*)out)[row * 256 + tid] = o;
    }
}

// ---------------------------------------------------------------------------
// Softmax over width 2048, bf16 in/out, IN-PLACE. One block per row.
// ---------------------------------------------------------------------------
__global__ __launch_bounds__(256)
void softmax2048_bf16(u16* io)
{
    const long row = blockIdx.x;
    const int tid = threadIdx.x;
    const us8 v = ((const us8*)io)[row * 256 + tid];
    float x[8];
#pragma unroll
    for (int i = 0; i < 8; ++i) x[i] = bf2f(v[i]);
    float m = x[0];
#pragma unroll
    for (int i = 1; i < 8; ++i) m = fmaxf(m, x[i]);
#pragma unroll
    for (int off = 32; off > 0; off >>= 1) m = fmaxf(m, __shfl_xor(m, off));
    __shared__ float rm[4], rsum[4];
    if ((tid & 63) == 0) rm[tid >> 6] = m;
    __syncthreads();
    m = fmaxf(fmaxf(rm[0], rm[1]), fmaxf(rm[2], rm[3]));
    float e[8];
    float s = 0.f;
#pragma unroll
    for (int i = 0; i < 8; ++i) { e[i] = __expf(x[i] - m); s += e[i]; }
#pragma unroll
    for (int off = 32; off > 0; off >>= 1) s += __shfl_xor(s, off);
    if ((tid & 63) == 0) rsum[tid >> 6] = s;
    __syncthreads();
    s = rsum[0] + rsum[1] + rsum[2] + rsum[3];
    const float inv = 1.0f / s;
    us8 o;
#pragma unroll
    for (int i = 0; i < 8; ++i) o[i] = f2bf(e[i] * inv);
    ((us8*)io)[row * 256 + tid] = o;
}

// fp32 -> bf16 cast, 8 elems/thread
__global__ __launch_bounds__(256)
void cast_f32_bf16(const float* __restrict__ in, u16* __restrict__ out, long n8)
{
    const long i = (long)blockIdx.x * 256 + threadIdx.x;
    if (i >= n8) return;
    const float4 a = ((const float4*)in)[i * 2];
    const float4 b = ((const float4*)in)[i * 2 + 1];
    us8 o;
    o[0] = f2bf(a.x); o[1] = f2bf(a.y); o[2] = f2bf(a.z); o[3] = f2bf(a.w);
    o[4] = f2bf(b.x); o[5] = f2bf(b.y); o[6] = f2bf(b.z); o[7] = f2bf(b.w);
    ((us8*)out)[i] = o;
}

// transpose + cast: fp32 [R,C] -> bf16 [C,R]. block (32,8), grid (C/32, R/32)
__global__ __launch_bounds__(256)
void tcast_f32_bf16(const float* __restrict__ in, u16* __restrict__ out,
                    int R, int C)
{
    __shared__ float t[32][33];
    const int tx = threadIdx.x, ty = threadIdx.y;
    const int c0 = blockIdx.x * 32, r0 = blockIdx.y * 32;
#pragma unroll
    for (int i = 0; i < 4; ++i)
        t[ty + i * 8][tx] = in[(long)(r0 + ty + i * 8) * C + c0 + tx];
    __syncthreads();
#pragma unroll
    for (int i = 0; i < 4; ++i)
        out[(long)(c0 + ty + i * 8) * R + r0 + tx] = f2bf(t[tx][ty + i * 8]);
}

// ---------------------------------------------------------------------------
extern "C" void kernel_launch(void* const* d_in, const int* in_sizes, int n_in,
                              void* d_out, int out_size, void* d_ws, size_t ws_size,
                              hipStream_t stream)
{
    const float* H_l      = (const float*)d_in[0];
    const float* H_a      = (const float*)d_in[1];
    const float* W_text   = (const float*)d_in[2];
    const float* b_text   = (const float*)d_in[3];
    const float* W_audio  = (const float*)d_in[4];
    const float* b_audio  = (const float*)d_in[5];
    const float* W_out    = (const float*)d_in[6];
    const float* b_out    = (const float*)d_in[7];
    const float* g1       = (const float*)d_in[8];
    const float* beta1    = (const float*)d_in[9];
    const float* g2       = (const float*)d_in[10];
    const float* beta2    = (const float*)d_in[11];
    const float* g_out    = (const float*)d_in[12];
    const float* beta_out = (const float*)d_in[13];
    (void)in_sizes; (void)n_in; (void)out_size;

    const int B = 16, L = 1024, S = 2048, DT = 1024, DA = 768, H = 1024;

    // ---------------- workspace layout (~245.5 MiB, heavy overlay) ---------
    char* ws = (char*)d_ws;
    const size_t SZ_HLB = (size_t)B * L * DT * 2;
    const size_t SZ_HAB = (size_t)B * S * DA * 2;
    const size_t O_A    = SZ_HLB + SZ_HAB;
    const size_t SZ_A   = (size_t)B * L * H * 2;
    const size_t O_C    = O_A + SZ_A;
    const size_t SZ_C   = (size_t)B * S * H * 2;
    const size_t O_D    = O_C + SZ_C;
    const size_t SZ_D   = (size_t)B * S * H * 2;
    const size_t O_W    = O_D + SZ_D;
    const size_t need   = O_W + (size_t)(DT * H + DA * H + H * H) * 2;

    if (ws_size < need) {
        fprintf(stderr, "[kernel_launch] ws_size=%zu < needed=%zu — aborting launches\n",
                ws_size, need);
        return;
    }

    u16*   Hlb     = (u16*)(ws);
    u16*   Hab     = (u16*)(ws + SZ_HLB);
    u16*   Scores  = (u16*)(ws);                 // overlays Hlb/Hab after G2
    u16*   Abuf    = (u16*)(ws + O_A);           // text_p -> Q -> Hh
    u16*   Vbuf    = (u16*)(ws + O_C);           // audio_p (LN2 input)
    u16*   Kbuf    = (u16*)(ws + O_D);           // K
    u16*   OutPre  = (u16*)(ws + O_D);           // out_pre bf16 (after K dies)
    u16*   Wt_text  = (u16*)(ws + O_W);
    u16*   Wt_audio = Wt_text + (size_t)DT * H;
    u16*   Wt_out   = Wt_audio + (size_t)DA * H;
    u16*   Vt      = (u16*)d_out;                // dies before final LN

    const float scale = 0.03125f; // 1/sqrt(1024)

    // input casts to bf16
    cast_f32_bf16<<<(B * L * DT / 8 + 255) / 256, 256, 0, stream>>>(H_l, Hlb, (long)B * L * DT / 8);
    cast_f32_bf16<<<(B * S * DA / 8 + 255) / 256, 256, 0, stream>>>(H_a, Hab, (long)B * S * DA / 8);
    // weight transposes [K,N] -> [N,K] bf16
    tcast_f32_bf16<<<dim3(H / 32, DT / 32), dim3(32, 8), 0, stream>>>(W_text, Wt_text, DT, H);
    tcast_f32_bf16<<<dim3(H / 32, DA / 32), dim3(32, 8), 0, stream>>>(W_audio, Wt_audio, DA, H);
    tcast_f32_bf16<<<dim3(H / 32, H / 32),  dim3(32, 8), 0, stream>>>(W_out, Wt_out, H, H);

    // G1: text_p = H_l @ W_text + b_text   [16384,1024] bf16
    gemm_nt<1, true, false, true, false><<<dim3(H / 128, B * L / 128, 1), 256, 0, stream>>>(
        Hlb, Wt_text, Abuf, b_text, nullptr, nullptr, DT, DT, DT, H, 0, 0, 0, 1.0f);
    // LN1 in-place: text_p -> Q
    ln1024<true, true><<<B * L, 256, 0, stream>>>(Abuf, g1, beta1, Abuf);

    // G2: audio_p = H_a @ W_audio + b_audio [32768,1024] bf16 (= V),
    //     epilogue also writes V^T into Vt (d_out) -> no transpose kernel
    gemm_nt<2, true, false, true, true><<<dim3(H / 128, B * S / 128, 1), 256, 0, stream>>>(
        Hab, Wt_audio, Vbuf, b_audio, nullptr, Vt, DA, DA, DA, H, 0, 0, 0, 1.0f);
    // LN2: audio_p -> K
    ln1024<true, true><<<B * S, 256, 0, stream>>>(Vbuf, g2, beta2, Kbuf);

    // G3: scores = Q @ K^T * scale          [B,1024,2048] bf16
    gemm_nt<3, false, false, true, false><<<dim3(S / 128, L / 128, B), 256, 0, stream>>>(
        Abuf, Kbuf, Scores, nullptr, nullptr, nullptr, H, H, H, S,
        (long)L * H, (long)S * H, (long)L * S, scale);

    // softmax in-place on bf16 scores -> alpha
    softmax2048_bf16<<<B * L, 256, 0, stream>>>(Scores);

    // G5: H_hyper = alpha @ V (NT vs Vt)    [B,1024,1024] bf16 -> Abuf (Q dead)
    gemm_nt<5, false, false, true, false><<<dim3(H / 128, L / 128, B), 256, 0, stream>>>(
        Scores, Vt, Abuf, nullptr, nullptr, nullptr, S, S, S, H,
        (long)L * S, (long)H * S, (long)L * H, 1.0f);

    // G6: out_pre = H_hyper @ W_out + b_out + H_l  [16384,1024] bf16 (K dead)
    gemm_nt<6, true, true, true, false><<<dim3(H / 128, B * L / 128, 1), 256, 0, stream>>>(
        Abuf, Wt_out, OutPre, b_out, H_l, nullptr, H, H, H, H, 0, 0, 0, 1.0f);

    // LN3 (bf16 in) -> d_out fp32 (Vt dead)
    ln1024<true, false><<<B * L, 256, 0, stream>>>(OutPre, g_out, beta_out, (float*)d_out);
}

// Round 11
// 494.385 us; speedup vs baseline: 1.2037x; 1.2037x over previous
//
#include <hip/hip_runtime.h>
#include <cstdio>

typedef unsigned short u16;
typedef __bf16 bf16x8 __attribute__((ext_vector_type(8)));
typedef float f32x4 __attribute__((ext_vector_type(4)));
typedef unsigned short us4 __attribute__((ext_vector_type(4)));
typedef unsigned short us8 __attribute__((ext_vector_type(8)));

__device__ __forceinline__ u16 f2bf(float f) {
    union { float f; unsigned u; } x; x.f = f;
    unsigned u = x.u + 0x7fffu + ((x.u >> 16) & 1u);   // RNE
    return (u16)(u >> 16);
}
__device__ __forceinline__ float bf2f(u16 u) {
    union { unsigned u; float f; } x; x.u = ((unsigned)u) << 16;
    return x.f;
}

// ---------------------------------------------------------------------------
// NT GEMM: C[M,N] = A[M,K] * B[N,K]^T, bf16 in, fp32 accumulate.
// 256x256 tile, BK=64, 512 threads (8 waves 2Mx4N, 128x64 per wave).
// Counted vmcnt: all of tile T+1's staging (8 global_load_lds/thread) issued
// at the TOP of iteration T; s_waitcnt vmcnt(8) waits only for tile T's loads.
// BARRIER-MINIMAL K-loop (2 barriers per K-tile): after the lead barrier, all
// 24 ds_read_b128 are issued, then all 64 MFMAs. No mid-tile barriers: the
// compiler's per-use lgkmcnt lets early MFMAs run while later reads drain
// (m97's overlap mechanism) — per-phase s_barriers were serializing LDS and
// MFMA pipes (R7-R9: ~7800 cy/K-tile vs ~2300 LDS + ~620 MFMA floors).
// LDS: 2 bufs x (A 32KB + B 32KB) = 128 KiB, XOR-swizzled rows
// (phys_koff = koff ^ ((row&7)<<4)); stage pre-swizzles the GLOBAL source so
// linear global_load_lds dest + swizzled ds_read agree (both-sides rule).
// Hazard ledger:
//   RAW global->LDS: each wave passes vmcnt(8) (tile T's loads done) then the
//     lead barrier -> all waves' loads landed before any ds_read of T.
//   WAR: every ds_read's consuming MFMA precedes the trailing barrier in
//     program order (consumption forces lgkmcnt completion), so all reads of
//     buf d are complete before any wave passes the trailing barrier;
//     stage(T+2) into buf d is issued only after the next lead barrier.
//   RAW LDS->MFMA: compiler-inserted fine-grained lgkmcnt (plain C++ loads).
// EMIT_VT (G2 only): epilogue additionally writes V^T[b][n][s].
// grid: (N/256, M/256, batch) flattened; nwg % 8 == 0 for the XCD remap.
// ---------------------------------------------------------------------------

#define LDFRAG(base, row, koff) \
  (*(const bf16x8*)((const char*)(base) + (size_t)(row) * 128 + \
                    ((koff) ^ (((row) & 7) << 4))))

template<int TAG, bool HAS_BIAS, bool HAS_RESID, bool OUT_BF16, bool EMIT_VT>
__global__ __launch_bounds__(512, 2)
void gemm_nt(const u16* __restrict__ A, const u16* __restrict__ Bm,
             void* __restrict__ Cm, const float* __restrict__ bias,
             const float* __restrict__ resid, u16* __restrict__ vt,
             int K, int lda, int ldb, int ldc,
             long sA, long sB, long sC, float scale)
{
    // [buf][256 rows][64 elem] per operand; rows are 128B, XOR-swizzled.
    __shared__ __align__(16) u16 lA[2 * 256 * 64];   // 64 KiB
    __shared__ __align__(16) u16 lB[2 * 256 * 64];   // 64 KiB

    const int tid = threadIdx.x;

    // ---- bijective XCD chunking over the flattened 3D grid (nwg%8==0) ----
    const int gx = gridDim.x, gy = gridDim.y;
    int flat = ((int)blockIdx.z * gy + blockIdx.y) * gx + blockIdx.x;
    const int nwg = gx * gy * (int)gridDim.z;
    const int q = nwg >> 3;
    flat = (flat & 7) * q + (flat >> 3);
    const int bx = flat % gx;
    const int t2 = flat / gx;
    const int by = t2 % gy;
    const long bz = t2 / gy;

    A  += bz * sA;
    Bm += bz * sB;
    const long cbase = bz * sC;
    const int m0 = by * 256;
    const int n0 = bx * 256;

    const int lane = tid & 63;
    const int w  = tid >> 6;                  // wave 0..7
    const int wr = w >> 2, wc = w & 3;        // 2x4 wave grid, 128x64 per wave
    const int fr = lane & 15;                 // A row / B col within fragment
    const int kg = lane >> 4;                 // k-group (0..3)

    // stage one half-tile (128 rows x 64 K = 16 KB) of operand op, half h,
    // K-tile kt, into buf d_. Global source pre-swizzled; LDS dest linear.
    auto stage_half = [&](int d_, int kt, int op, int h) {
        const u16* src = op ? Bm : A;
        const int  ld  = op ? ldb : lda;
        const int  bs  = op ? n0 : m0;
        u16* lds = (op ? lB : lA) + d_ * 16384 + h * 8192;
#pragma unroll
        for (int i2 = 0; i2 < 2; ++i2) {
            const int c  = i2 * 512 + tid;            // 16B chunk id, 0..1023
            const int r  = c >> 3;                    // row within half
            const int kb = ((c & 7) * 16) ^ ((r & 7) << 4);   // pre-swizzled k byte
            const u16* g = src + (size_t)(bs + h * 128 + r) * ld + kt * 64 + (kb >> 1);
            __builtin_amdgcn_global_load_lds(
                (const __attribute__((address_space(1))) void*)g,
                (__attribute__((address_space(3))) void*)(lds + (size_t)c * 8), 16, 0, 0);
        }
    };
    // full K-tile: 4 halves = 8 global_load_lds per thread (vmcnt +8)
    auto stage_tile = [&](int d_, int kt) {
        stage_half(d_, kt, 0, 0); stage_half(d_, kt, 0, 1);
        stage_half(d_, kt, 1, 0); stage_half(d_, kt, 1, 1);
    };

    f32x4 acc[8][4] = {};

    const int nt = K >> 6;
    stage_tile(0, 0);                         // pipeline fill (only cold wait)

    for (int T = 0; T < nt; ++T) {
        const int d = T & 1;
        const u16* pA = lA + d * 16384;
        const u16* pB = lB + d * 16384;

        // ---- K-tile top: issue T+1's staging, counted wait on T's ----
        if (T + 1 < nt) {
            stage_tile(d ^ 1, T + 1);
            asm volatile("s_waitcnt vmcnt(8)" ::: "memory");   // oldest 8 = tile T
        } else {
            asm volatile("s_waitcnt vmcnt(0)" ::: "memory");   // final drain
        }
        __builtin_amdgcn_s_barrier();         // all waves' tile-T loads landed
        asm volatile("" ::: "memory");

        // ---- all 24 ds_read_b128 for this K-tile (compiler pipelines) ----
        bf16x8 af0[4][2], af1[4][2], bfr0[2][2], bfr1[2][2];
#pragma unroll
        for (int j = 0; j < 4; ++j)
#pragma unroll
            for (int ks = 0; ks < 2; ++ks)
                af0[j][ks] = LDFRAG(pA, wr * 128 + j * 16 + fr, ks * 64 + kg * 16);
#pragma unroll
        for (int i = 0; i < 2; ++i)
#pragma unroll
            for (int ks = 0; ks < 2; ++ks)
                bfr0[i][ks] = LDFRAG(pB, wc * 64 + i * 16 + fr, ks * 64 + kg * 16);
#pragma unroll
        for (int i = 0; i < 2; ++i)
#pragma unroll
            for (int ks = 0; ks < 2; ++ks)
                bfr1[i][ks] = LDFRAG(pB, wc * 64 + 32 + i * 16 + fr, ks * 64 + kg * 16);
#pragma unroll
        for (int j = 0; j < 4; ++j)
#pragma unroll
            for (int ks = 0; ks < 2; ++ks)
                af1[j][ks] = LDFRAG(pA, wr * 128 + 64 + j * 16 + fr, ks * 64 + kg * 16);

        // ---- all 64 MFMAs, quadrant order matching read order ----
        __builtin_amdgcn_s_setprio(1);
#pragma unroll
        for (int j = 0; j < 4; ++j)
#pragma unroll
            for (int i = 0; i < 2; ++i)
#pragma unroll
                for (int ks = 0; ks < 2; ++ks)
                    acc[j][i] = __builtin_amdgcn_mfma_f32_16x16x32_bf16(
                        af0[j][ks], bfr0[i][ks], acc[j][i], 0, 0, 0);
#pragma unroll
        for (int j = 0; j < 4; ++j)
#pragma unroll
            for (int i = 0; i < 2; ++i)
#pragma unroll
                for (int ks = 0; ks < 2; ++ks)
                    acc[j][2 + i] = __builtin_amdgcn_mfma_f32_16x16x32_bf16(
                        af0[j][ks], bfr1[i][ks], acc[j][2 + i], 0, 0, 0);
#pragma unroll
        for (int j = 0; j < 4; ++j)
#pragma unroll
            for (int i = 0; i < 2; ++i)
#pragma unroll
                for (int ks = 0; ks < 2; ++ks)
                    acc[4 + j][i] = __builtin_amdgcn_mfma_f32_16x16x32_bf16(
                        af1[j][ks], bfr0[i][ks], acc[4 + j][i], 0, 0, 0);
#pragma unroll
        for (int j = 0; j < 4; ++j)
#pragma unroll
            for (int i = 0; i < 2; ++i)
#pragma unroll
                for (int ks = 0; ks < 2; ++ks)
                    acc[4 + j][2 + i] = __builtin_amdgcn_mfma_f32_16x16x32_bf16(
                        af1[j][ks], bfr1[i][ks], acc[4 + j][2 + i], 0, 0, 0);
        __builtin_amdgcn_s_setprio(0);

        asm volatile("" ::: "memory");
        __builtin_amdgcn_s_barrier();         // all reads of buf d consumed
        asm volatile("" ::: "memory");        // before stage(T+2) overwrites
    }

    // epilogue: C/D layout col=lane&15, row=(lane>>4)*4+reg  [m89-verified]
    const int orow = m0 + wr * 128 + kg * 4;
    const int ocol = n0 + wc * 64 + fr;
#pragma unroll
    for (int mf = 0; mf < 8; ++mf) {
        const int mbase = orow + mf * 16;     // 4 consecutive rows mbase..+3
#pragma unroll
        for (int nf = 0; nf < 4; ++nf) {
            const int n = ocol + nf * 16;
            float v4[4];
#pragma unroll
            for (int r = 0; r < 4; ++r) {
                const int m = mbase + r;
                float v = acc[mf][nf][r] * scale;
                if (HAS_BIAS)  v += bias[n];
                if (HAS_RESID) v += resid[cbase + (long)m * ldc + n];
                v4[r] = v;
                if (OUT_BF16)  ((u16*)Cm)[cbase + (long)m * ldc + n] = f2bf(v);
                else           ((float*)Cm)[cbase + (long)m * ldc + n] = v;
            }
            if (EMIT_VT) {
                // rows m = b*2048 + s; write Vt[b][n][s..s+3] (batch S=2048)
                const long b_ = mbase >> 11;
                const int  s  = mbase & 2047;
                us4 o;
#pragma unroll
                for (int r = 0; r < 4; ++r) o[r] = f2bf(v4[r]);
                *(us4*)(vt + (b_ * 1024 + n) * 2048 + s) = o;
            }
        }
    }
}

// ---------------------------------------------------------------------------
// LayerNorm over D=1024, one block (256 thr) per row.
// ---------------------------------------------------------------------------
template<bool IN_BF16, bool OUT_BF16>
__global__ __launch_bounds__(256)
void ln1024(const void* in, const float* __restrict__ g,
            const float* __restrict__ beta, void* out)
{
    const long row = blockIdx.x;
    const int tid = threadIdx.x;
    float x0, x1, x2, x3;
    if (IN_BF16) {
        const us4 v = ((const us4*)in)[row * 256 + tid];
        x0 = bf2f(v[0]); x1 = bf2f(v[1]); x2 = bf2f(v[2]); x3 = bf2f(v[3]);
    } else {
        const float4 v = ((const float4*)in)[row * 256 + tid];
        x0 = v.x; x1 = v.y; x2 = v.z; x3 = v.w;
    }
    float s  = x0 + x1 + x2 + x3;
    float s2 = x0 * x0 + x1 * x1 + x2 * x2 + x3 * x3;
#pragma unroll
    for (int off = 32; off > 0; off >>= 1) {
        s  += __shfl_xor(s, off);
        s2 += __shfl_xor(s2, off);
    }
    __shared__ float rs[4], rq[4];
    if ((tid & 63) == 0) { rs[tid >> 6] = s; rq[tid >> 6] = s2; }
    __syncthreads();
    const float S  = rs[0] + rs[1] + rs[2] + rs[3];
    const float S2 = rq[0] + rq[1] + rq[2] + rq[3];
    const float mu = S * (1.0f / 1024.0f);
    const float var = S2 * (1.0f / 1024.0f) - mu * mu;
    const float rstd = rsqrtf(var + 1e-5f);
    const float4 gg = ((const float4*)g)[tid];
    const float4 bb = ((const float4*)beta)[tid];
    const float y0 = (x0 - mu) * rstd * gg.x + bb.x;
    const float y1 = (x1 - mu) * rstd * gg.y + bb.y;
    const float y2 = (x2 - mu) * rstd * gg.z + bb.z;
    const float y3 = (x3 - mu) * rstd * gg.w + bb.w;
    if (OUT_BF16) {
        us4 o; o[0] = f2bf(y0); o[1] = f2bf(y1); o[2] = f2bf(y2); o[3] = f2bf(y3);
        ((us4*)out)[row * 256 + tid] = o;
    } else {
        float4 o; o.x = y0; o.y = y1; o.z = y2; o.w = y3;
        ((float4*)out)[row * 256 + tid] = o;
    }
}

// ---------------------------------------------------------------------------
// Softmax over width 2048, bf16 in/out, IN-PLACE. One block per row.
// ---------------------------------------------------------------------------
__global__ __launch_bounds__(256)
void softmax2048_bf16(u16* io)
{
    const long row = blockIdx.x;
    const int tid = threadIdx.x;
    const us8 v = ((const us8*)io)[row * 256 + tid];
    float x[8];
#pragma unroll
    for (int i = 0; i < 8; ++i) x[i] = bf2f(v[i]);
    float m = x[0];
#pragma unroll
    for (int i = 1; i < 8; ++i) m = fmaxf(m, x[i]);
#pragma unroll
    for (int off = 32; off > 0; off >>= 1) m = fmaxf(m, __shfl_xor(m, off));
    __shared__ float rm[4], rsum[4];
    if ((tid & 63) == 0) rm[tid >> 6] = m;
    __syncthreads();
    m = fmaxf(fmaxf(rm[0], rm[1]), fmaxf(rm[2], rm[3]));
    float e[8];
    float s = 0.f;
#pragma unroll
    for (int i = 0; i < 8; ++i) { e[i] = __expf(x[i] - m); s += e[i]; }
#pragma unroll
    for (int off = 32; off > 0; off >>= 1) s += __shfl_xor(s, off);
    if ((tid & 63) == 0) rsum[tid >> 6] = s;
    __syncthreads();
    s = rsum[0] + rsum[1] + rsum[2] + rsum[3];
    const float inv = 1.0f / s;
    us8 o;
#pragma unroll
    for (int i = 0; i < 8; ++i) o[i] = f2bf(e[i] * inv);
    ((us8*)io)[row * 256 + tid] = o;
}

// fp32 -> bf16 cast, 8 elems/thread
__global__ __launch_bounds__(256)
void cast_f32_bf16(const float* __restrict__ in, u16* __restrict__ out, long n8)
{
    const long i = (long)blockIdx.x * 256 + threadIdx.x;
    if (i >= n8) return;
    const float4 a = ((const float4*)in)[i * 2];
    const float4 b = ((const float4*)in)[i * 2 + 1];
    us8 o;
    o[0] = f2bf(a.x); o[1] = f2bf(a.y); o[2] = f2bf(a.z); o[3] = f2bf(a.w);
    o[4] = f2bf(b.x); o[5] = f2bf(b.y); o[6] = f2bf(b.z); o[7] = f2bf(b.w);
    ((us8*)out)[i] = o;
}

// transpose + cast: fp32 [R,C] -> bf16 [C,R]. block (32,8), grid (C/32, R/32)
__global__ __launch_bounds__(256)
void tcast_f32_bf16(const float* __restrict__ in, u16* __restrict__ out,
                    int R, int C)
{
    __shared__ float t[32][33];
    const int tx = threadIdx.x, ty = threadIdx.y;
    const int c0 = blockIdx.x * 32, r0 = blockIdx.y * 32;
#pragma unroll
    for (int i = 0; i < 4; ++i)
        t[ty + i * 8][tx] = in[(long)(r0 + ty + i * 8) * C + c0 + tx];
    __syncthreads();
#pragma unroll
    for (int i = 0; i < 4; ++i)
        out[(long)(c0 + ty + i * 8) * R + r0 + tx] = f2bf(t[tx][ty + i * 8]);
}

// ---------------------------------------------------------------------------
extern "C" void kernel_launch(void* const* d_in, const int* in_sizes, int n_in,
                              void* d_out, int out_size, void* d_ws, size_t ws_size,
                              hipStream_t stream)
{
    const float* H_l      = (const float*)d_in[0];
    const float* H_a      = (const float*)d_in[1];
    const float* W_text   = (const float*)d_in[2];
    const float* b_text   = (const float*)d_in[3];
    const float* W_audio  = (const float*)d_in[4];
    const float* b_audio  = (const float*)d_in[5];
    const float* W_out    = (const float*)d_in[6];
    const float* b_out    = (const float*)d_in[7];
    const float* g1       = (const float*)d_in[8];
    const float* beta1    = (const float*)d_in[9];
    const float* g2       = (const float*)d_in[10];
    const float* beta2    = (const float*)d_in[11];
    const float* g_out    = (const float*)d_in[12];
    const float* beta_out = (const float*)d_in[13];
    (void)in_sizes; (void)n_in; (void)out_size;

    const int B = 16, L = 1024, S = 2048, DT = 1024, DA = 768, H = 1024;

    // ---------------- workspace layout (~245.5 MiB, heavy overlay) ---------
    char* ws = (char*)d_ws;
    const size_t SZ_HLB = (size_t)B * L * DT * 2;
    const size_t SZ_HAB = (size_t)B * S * DA * 2;
    const size_t O_A    = SZ_HLB + SZ_HAB;
    const size_t SZ_A   = (size_t)B * L * H * 2;
    const size_t O_C    = O_A + SZ_A;
    const size_t SZ_C   = (size_t)B * S * H * 2;
    const size_t O_D    = O_C + SZ_C;
    const size_t SZ_D   = (size_t)B * S * H * 2;
    const size_t O_W    = O_D + SZ_D;
    const size_t need   = O_W + (size_t)(DT * H + DA * H + H * H) * 2;

    if (ws_size < need) {
        fprintf(stderr, "[kernel_launch] ws_size=%zu < needed=%zu — aborting launches\n",
                ws_size, need);
        return;
    }

    u16*   Hlb     = (u16*)(ws);
    u16*   Hab     = (u16*)(ws + SZ_HLB);
    u16*   Scores  = (u16*)(ws);                 // overlays Hlb/Hab after G2
    u16*   Abuf    = (u16*)(ws + O_A);           // text_p -> Q -> Hh
    u16*   Vbuf    = (u16*)(ws + O_C);           // audio_p (LN2 input)
    u16*   Kbuf    = (u16*)(ws + O_D);           // K
    u16*   OutPre  = (u16*)(ws + O_D);           // out_pre bf16 (after K dies)
    u16*   Wt_text  = (u16*)(ws + O_W);
    u16*   Wt_audio = Wt_text + (size_t)DT * H;
    u16*   Wt_out   = Wt_audio + (size_t)DA * H;
    u16*   Vt      = (u16*)d_out;                // dies before final LN

    const float scale = 0.03125f; // 1/sqrt(1024)

    // input casts to bf16
    cast_f32_bf16<<<(B * L * DT / 8 + 255) / 256, 256, 0, stream>>>(H_l, Hlb, (long)B * L * DT / 8);
    cast_f32_bf16<<<(B * S * DA / 8 + 255) / 256, 256, 0, stream>>>(H_a, Hab, (long)B * S * DA / 8);
    // weight transposes [K,N] -> [N,K] bf16
    tcast_f32_bf16<<<dim3(H / 32, DT / 32), dim3(32, 8), 0, stream>>>(W_text, Wt_text, DT, H);
    tcast_f32_bf16<<<dim3(H / 32, DA / 32), dim3(32, 8), 0, stream>>>(W_audio, Wt_audio, DA, H);
    tcast_f32_bf16<<<dim3(H / 32, H / 32),  dim3(32, 8), 0, stream>>>(W_out, Wt_out, H, H);

    // G1: text_p = H_l @ W_text + b_text   [16384,1024] bf16
    gemm_nt<1, true, false, true, false><<<dim3(H / 256, B * L / 256, 1), 512, 0, stream>>>(
        Hlb, Wt_text, Abuf, b_text, nullptr, nullptr, DT, DT, DT, H, 0, 0, 0, 1.0f);
    // LN1 in-place: text_p -> Q
    ln1024<true, true><<<B * L, 256, 0, stream>>>(Abuf, g1, beta1, Abuf);

    // G2: audio_p = H_a @ W_audio + b_audio [32768,1024] bf16 (= V),
    //     epilogue also writes V^T into Vt (d_out) -> no transpose kernel
    gemm_nt<2, true, false, true, true><<<dim3(H / 256, B * S / 256, 1), 512, 0, stream>>>(
        Hab, Wt_audio, Vbuf, b_audio, nullptr, Vt, DA, DA, DA, H, 0, 0, 0, 1.0f);
    // LN2: audio_p -> K
    ln1024<true, true><<<B * S, 256, 0, stream>>>(Vbuf, g2, beta2, Kbuf);

    // G3: scores = Q @ K^T * scale          [B,1024,2048] bf16
    gemm_nt<3, false, false, true, false><<<dim3(S / 256, L / 256, B), 512, 0, stream>>>(
        Abuf, Kbuf, Scores, nullptr, nullptr, nullptr, H, H, H, S,
        (long)L * H, (long)S * H, (long)L * S, scale);

    // softmax in-place on bf16 scores -> alpha
    softmax2048_bf16<<<B * L, 256, 0, stream>>>(Scores);

    // G5: H_hyper = alpha @ V (NT vs Vt)    [B,1024,1024] bf16 -> Abuf (Q dead)
    gemm_nt<5, false, false, true, false><<<dim3(H / 256, L / 256, B), 512, 0, stream>>>(
        Scores, Vt, Abuf, nullptr, nullptr, nullptr, S, S, S, H,
        (long)L * S, (long)H * S, (long)L * H, 1.0f);

    // G6: out_pre = H_hyper @ W_out + b_out + H_l  [16384,1024] bf16 (K dead)
    gemm_nt<6, true, true, true, false><<<dim3(H / 256, B * L / 256, 1), 512, 0, stream>>>(
        Abuf, Wt_out, OutPre, b_out, H_l, nullptr, H, H, H, H, 0, 0, 0, 1.0f);

    // LN3 (bf16 in) -> d_out fp32 (Vt dead)
    ln1024<true, false><<<B * L, 256, 0, stream>>>(OutPre, g_out, beta_out, (float*)d_out);
}

// Round 12
// 476.454 us; speedup vs baseline: 1.2490x; 1.0376x over previous
//
#include <hip/hip_runtime.h>
#include <cstdio>

typedef unsigned short u16;
typedef __bf16 bf16x8 __attribute__((ext_vector_type(8)));
typedef float f32x4 __attribute__((ext_vector_type(4)));
typedef unsigned short us4 __attribute__((ext_vector_type(4)));
typedef unsigned short us8 __attribute__((ext_vector_type(8)));

__device__ __forceinline__ u16 f2bf(float f) {
    union { float f; unsigned u; } x; x.f = f;
    unsigned u = x.u + 0x7fffu + ((x.u >> 16) & 1u);   // RNE
    return (u16)(u >> 16);
}
__device__ __forceinline__ float bf2f(u16 u) {
    union { unsigned u; float f; } x; x.u = ((unsigned)u) << 16;
    return x.f;
}

// ---------------------------------------------------------------------------
// NT GEMM: C[M,N] = A[M,K] * B[N,K]^T, bf16 in, fp32 accumulate.
// 256x256 tile, BK=64, 512 threads (8 waves 2Mx4N, 128x64 per wave).
// m201-style 4-phase/K-tile schedule with a 4-slot HALF-TILE RING per
// operand (slot(tile T, half h) = (2T+h)&3, 16 KB each; tile T+2 reuses
// tile T's slots):
//   p1: ds_read af0(8)+bfr0(4)            ; BAR ; prio1 ; 16 MFMA Q00 ; BAR
//   p2: ds_read bfr1(4)                   ; BAR ; prio1 ; 16 MFMA Q01 ; BAR
//   p3: ds_read af1(8) ; stage B(T+2) x2  ; BAR ; prio1 ; 16 MFMA Q10 ; BAR
//   p4: stage A(T+2) x2                   ; BAR ; prio1 ; 16 MFMA Q11 ; BAR
// Counted vmcnt at iter top: vmcnt(8) = iter T-1's 8 loads stay in flight,
// everything older (tile T's data) landed. Tail iter: vmcnt(0) (iter nt-2
// stages nothing, so count-8 would skip the final tile's wait).
// No lgkmcnt(0)/sched_barrier: ds_reads are plain C++ loads; the compiler
// emits fine-grained per-fragment lgkmcnt (R11 evidence: pinning costs ~1.7x).
// Hazard ledger:
//   RAW global->LDS: each wave passes its own vmcnt at iter top, then the
//     top barrier -> all waves' tile-T loads landed before any ds_read of T.
//   WAR (ring): B slots of tile T last ds_read at p2, consumed by p2's MFMA
//     before p2's trailing barrier -> stage into them at p3 is safe. A slots
//     last read at p3 -> staged at p4. Regs (bfr0, af0) outlive the slot
//     overwrite -- only LDS is recycled.
//   RAW LDS->MFMA: compiler-inserted lgkmcnt before first consuming MFMA.
// LDS: 2 x 64 KiB, XOR-swizzled rows (phys_koff = koff ^ ((row&7)<<4));
// stage pre-swizzles the GLOBAL source (both-sides rule).
// EMIT_VT (G2 only): epilogue additionally writes V^T[b][n][s].
// grid: (N/256, M/256, batch) flattened; nwg % 8 == 0 for the XCD remap.
// Requires nt >= 3 (smallest K here is 768 -> nt=12).
// ---------------------------------------------------------------------------

#define LDFRAG(base, row, koff) \
  (*(const bf16x8*)((const char*)(base) + (size_t)(row) * 128 + \
                    ((koff) ^ (((row) & 7) << 4))))

#define BAR() do { \
  asm volatile("" ::: "memory"); \
  __builtin_amdgcn_s_barrier(); \
  asm volatile("" ::: "memory"); \
} while (0)

#define MFMA16(AF, BF, MO, NO) do { \
  __builtin_amdgcn_s_setprio(1); \
  _Pragma("unroll") for (int j = 0; j < 4; ++j) \
    _Pragma("unroll") for (int i = 0; i < 2; ++i) \
      _Pragma("unroll") for (int ks = 0; ks < 2; ++ks) \
        acc[(MO) + j][(NO) + i] = __builtin_amdgcn_mfma_f32_16x16x32_bf16( \
            AF[j][ks], BF[i][ks], acc[(MO) + j][(NO) + i], 0, 0, 0); \
  __builtin_amdgcn_s_setprio(0); \
} while (0)

template<int TAG, bool HAS_BIAS, bool HAS_RESID, bool OUT_BF16, bool EMIT_VT>
__global__ __launch_bounds__(512, 2)
void gemm_nt(const u16* __restrict__ A, const u16* __restrict__ Bm,
             void* __restrict__ Cm, const float* __restrict__ bias,
             const float* __restrict__ resid, u16* __restrict__ vt,
             int K, int lda, int ldb, int ldc,
             long sA, long sB, long sC, float scale)
{
    // 4 half-tile slots per operand, 8192 u16 (16 KB) each; rows 128B swz.
    __shared__ __align__(16) u16 lA[4 * 128 * 64];   // 64 KiB
    __shared__ __align__(16) u16 lB[4 * 128 * 64];   // 64 KiB

    const int tid = threadIdx.x;

    // ---- bijective XCD chunking over the flattened 3D grid (nwg%8==0) ----
    const int gx = gridDim.x, gy = gridDim.y;
    int flat = ((int)blockIdx.z * gy + blockIdx.y) * gx + blockIdx.x;
    const int nwg = gx * gy * (int)gridDim.z;
    const int q = nwg >> 3;
    flat = (flat & 7) * q + (flat >> 3);
    const int bx = flat % gx;
    const int t2 = flat / gx;
    const int by = t2 % gy;
    const long bz = t2 / gy;

    A  += bz * sA;
    Bm += bz * sB;
    const long cbase = bz * sC;
    const int m0 = by * 256;
    const int n0 = bx * 256;

    const int lane = tid & 63;
    const int w  = tid >> 6;                  // wave 0..7
    const int wr = w >> 2, wc = w & 3;        // 2x4 wave grid, 128x64 per wave
    const int fr = lane & 15;                 // A row / B col within fragment
    const int kg = lane >> 4;                 // k-group (0..3)

    // stage one half-tile (128 rows x 64 K = 16 KB) of operand op, half h,
    // K-tile kt, into ring slot (2*kt+h)&3. Global source pre-swizzled;
    // LDS dest linear. 2 global_load_lds per thread per call.
    auto stage_half = [&](int kt, int op, int h) {
        const u16* src = op ? Bm : A;
        const int  ld  = op ? ldb : lda;
        const int  bs  = op ? n0 : m0;
        u16* lds = (op ? lB : lA) + (size_t)(((2 * kt + h) & 3)) * 8192;
#pragma unroll
        for (int i2 = 0; i2 < 2; ++i2) {
            const int c  = i2 * 512 + tid;            // 16B chunk id, 0..1023
            const int r  = c >> 3;                    // row within half
            const int kb = ((c & 7) * 16) ^ ((r & 7) << 4);   // pre-swizzled k byte
            const u16* g = src + (size_t)(bs + h * 128 + r) * ld + kt * 64 + (kb >> 1);
            __builtin_amdgcn_global_load_lds(
                (const __attribute__((address_space(1))) void*)g,
                (__attribute__((address_space(3))) void*)(lds + (size_t)c * 8), 16, 0, 0);
        }
    };
    auto stage_tile = [&](int kt) {
        stage_half(kt, 0, 0); stage_half(kt, 0, 1);
        stage_half(kt, 1, 0); stage_half(kt, 1, 1);
    };

    f32x4 acc[8][4] = {};

    const int nt = K >> 6;                    // nt >= 12 for all GEMMs here
    stage_tile(0);                            // slots A/B 0,1
    stage_tile(1);                            // slots A/B 2,3

    const int bRowBase = (wc & 1) * 64;       // B local row base within slot

    for (int T = 0; T < nt; ++T) {
        // ---- iter top: tile T's staging landed (all waves) ----
        if (T == nt - 1) asm volatile("s_waitcnt vmcnt(0)" ::: "memory");
        else             asm volatile("s_waitcnt vmcnt(8)" ::: "memory");
        BAR();

        const u16* pA = lA + (size_t)(((2 * T + wr) & 3)) * 8192;
        const u16* pB = lB + (size_t)(((2 * T + (wc >> 1)) & 3)) * 8192;
        const bool pre = (T + 2 < nt);

        bf16x8 af0[4][2], af1[4][2], bfr0[2][2], bfr1[2][2];

        // ---- phase 1: read af0 (rows 0-63 of wave half) + bfr0 ; Q00 ----
#pragma unroll
        for (int j = 0; j < 4; ++j)
#pragma unroll
            for (int ks = 0; ks < 2; ++ks)
                af0[j][ks] = LDFRAG(pA, j * 16 + fr, ks * 64 + kg * 16);
#pragma unroll
        for (int i = 0; i < 2; ++i)
#pragma unroll
            for (int ks = 0; ks < 2; ++ks)
                bfr0[i][ks] = LDFRAG(pB, bRowBase + i * 16 + fr, ks * 64 + kg * 16);
        BAR();
        MFMA16(af0, bfr0, 0, 0);
        BAR();

        // ---- phase 2: read bfr1 ; Q01 ----
#pragma unroll
        for (int i = 0; i < 2; ++i)
#pragma unroll
            for (int ks = 0; ks < 2; ++ks)
                bfr1[i][ks] = LDFRAG(pB, bRowBase + 32 + i * 16 + fr, ks * 64 + kg * 16);
        BAR();
        MFMA16(af0, bfr1, 0, 2);
        BAR();

        // ---- phase 3: read af1 (rows 64-127) ; stage B halves of T+2 ; Q10
        //      (B slots of tile T were last read in p2 -> free now)
#pragma unroll
        for (int j = 0; j < 4; ++j)
#pragma unroll
            for (int ks = 0; ks < 2; ++ks)
                af1[j][ks] = LDFRAG(pA, 64 + j * 16 + fr, ks * 64 + kg * 16);
        if (pre) { stage_half(T + 2, 1, 0); stage_half(T + 2, 1, 1); }
        BAR();
        MFMA16(af1, bfr0, 4, 0);
        BAR();

        // ---- phase 4: stage A halves of T+2 ; Q11
        //      (A slots of tile T were last read in p3 -> free now)
        if (pre) { stage_half(T + 2, 0, 0); stage_half(T + 2, 0, 1); }
        BAR();
        MFMA16(af1, bfr1, 4, 2);
        BAR();
    }

    // epilogue: C/D layout col=lane&15, row=(lane>>4)*4+reg  [m89-verified]
    const int orow = m0 + wr * 128 + kg * 4;
    const int ocol = n0 + wc * 64 + fr;
#pragma unroll
    for (int mf = 0; mf < 8; ++mf) {
        const int mbase = orow + mf * 16;     // 4 consecutive rows mbase..+3
#pragma unroll
        for (int nf = 0; nf < 4; ++nf) {
            const int n = ocol + nf * 16;
            float v4[4];
#pragma unroll
            for (int r = 0; r < 4; ++r) {
                const int m = mbase + r;
                float v = acc[mf][nf][r] * scale;
                if (HAS_BIAS)  v += bias[n];
                if (HAS_RESID) v += resid[cbase + (long)m * ldc + n];
                v4[r] = v;
                if (OUT_BF16)  ((u16*)Cm)[cbase + (long)m * ldc + n] = f2bf(v);
                else           ((float*)Cm)[cbase + (long)m * ldc + n] = v;
            }
            if (EMIT_VT) {
                // rows m = b*2048 + s; write Vt[b][n][s..s+3] (batch S=2048)
                const long b_ = mbase >> 11;
                const int  s  = mbase & 2047;
                us4 o;
#pragma unroll
                for (int r = 0; r < 4; ++r) o[r] = f2bf(v4[r]);
                *(us4*)(vt + (b_ * 1024 + n) * 2048 + s) = o;
            }
        }
    }
}

// ---------------------------------------------------------------------------
// LayerNorm over D=1024, one block (256 thr) per row.
// ---------------------------------------------------------------------------
template<bool IN_BF16, bool OUT_BF16>
__global__ __launch_bounds__(256)
void ln1024(const void* in, const float* __restrict__ g,
            const float* __restrict__ beta, void* out)
{
    const long row = blockIdx.x;
    const int tid = threadIdx.x;
    float x0, x1, x2, x3;
    if (IN_BF16) {
        const us4 v = ((const us4*)in)[row * 256 + tid];
        x0 = bf2f(v[0]); x1 = bf2f(v[1]); x2 = bf2f(v[2]); x3 = bf2f(v[3]);
    } else {
        const float4 v = ((const float4*)in)[row * 256 + tid];
        x0 = v.x; x1 = v.y; x2 = v.z; x3 = v.w;
    }
    float s  = x0 + x1 + x2 + x3;
    float s2 = x0 * x0 + x1 * x1 + x2 * x2 + x3 * x3;
#pragma unroll
    for (int off = 32; off > 0; off >>= 1) {
        s  += __shfl_xor(s, off);
        s2 += __shfl_xor(s2, off);
    }
    __shared__ float rs[4], rq[4];
    if ((tid & 63) == 0) { rs[tid >> 6] = s; rq[tid >> 6] = s2; }
    __syncthreads();
    const float S  = rs[0] + rs[1] + rs[2] + rs[3];
    const float S2 = rq[0] + rq[1] + rq[2] + rq[3];
    const float mu = S * (1.0f / 1024.0f);
    const float var = S2 * (1.0f / 1024.0f) - mu * mu;
    const float rstd = rsqrtf(var + 1e-5f);
    const float4 gg = ((const float4*)g)[tid];
    const float4 bb = ((const float4*)beta)[tid];
    const float y0 = (x0 - mu) * rstd * gg.x + bb.x;
    const float y1 = (x1 - mu) * rstd * gg.y + bb.y;
    const float y2 = (x2 - mu) * rstd * gg.z + bb.z;
    const float y3 = (x3 - mu) * rstd * gg.w + bb.w;
    if (OUT_BF16) {
        us4 o; o[0] = f2bf(y0); o[1] = f2bf(y1); o[2] = f2bf(y2); o[3] = f2bf(y3);
        ((us4*)out)[row * 256 + tid] = o;
    } else {
        float4 o; o.x = y0; o.y = y1; o.z = y2; o.w = y3;
        ((float4*)out)[row * 256 + tid] = o;
    }
}

// ---------------------------------------------------------------------------
// Softmax over width 2048, bf16 in/out, IN-PLACE. One block per row.
// ---------------------------------------------------------------------------
__global__ __launch_bounds__(256)
void softmax2048_bf16(u16* io)
{
    const long row = blockIdx.x;
    const int tid = threadIdx.x;
    const us8 v = ((const us8*)io)[row * 256 + tid];
    float x[8];
#pragma unroll
    for (int i = 0; i < 8; ++i) x[i] = bf2f(v[i]);
    float m = x[0];
#pragma unroll
    for (int i = 1; i < 8; ++i) m = fmaxf(m, x[i]);
#pragma unroll
    for (int off = 32; off > 0; off >>= 1) m = fmaxf(m, __shfl_xor(m, off));
    __shared__ float rm[4], rsum[4];
    if ((tid & 63) == 0) rm[tid >> 6] = m;
    __syncthreads();
    m = fmaxf(fmaxf(rm[0], rm[1]), fmaxf(rm[2], rm[3]));
    float e[8];
    float s = 0.f;
#pragma unroll
    for (int i = 0; i < 8; ++i) { e[i] = __expf(x[i] - m); s += e[i]; }
#pragma unroll
    for (int off = 32; off > 0; off >>= 1) s += __shfl_xor(s, off);
    if ((tid & 63) == 0) rsum[tid >> 6] = s;
    __syncthreads();
    s = rsum[0] + rsum[1] + rsum[2] + rsum[3];
    const float inv = 1.0f / s;
    us8 o;
#pragma unroll
    for (int i = 0; i < 8; ++i) o[i] = f2bf(e[i] * inv);
    ((us8*)io)[row * 256 + tid] = o;
}

// fp32 -> bf16 cast, 8 elems/thread
__global__ __launch_bounds__(256)
void cast_f32_bf16(const float* __restrict__ in, u16* __restrict__ out, long n8)
{
    const long i = (long)blockIdx.x * 256 + threadIdx.x;
    if (i >= n8) return;
    const float4 a = ((const float4*)in)[i * 2];
    const float4 b = ((const float4*)in)[i * 2 + 1];
    us8 o;
    o[0] = f2bf(a.x); o[1] = f2bf(a.y); o[2] = f2bf(a.z); o[3] = f2bf(a.w);
    o[4] = f2bf(b.x); o[5] = f2bf(b.y); o[6] = f2bf(b.z); o[7] = f2bf(b.w);
    ((us8*)out)[i] = o;
}

// transpose + cast: fp32 [R,C] -> bf16 [C,R]. block (32,8), grid (C/32, R/32)
__global__ __launch_bounds__(256)
void tcast_f32_bf16(const float* __restrict__ in, u16* __restrict__ out,
                    int R, int C)
{
    __shared__ float t[32][33];
    const int tx = threadIdx.x, ty = threadIdx.y;
    const int c0 = blockIdx.x * 32, r0 = blockIdx.y * 32;
#pragma unroll
    for (int i = 0; i < 4; ++i)
        t[ty + i * 8][tx] = in[(long)(r0 + ty + i * 8) * C + c0 + tx];
    __syncthreads();
#pragma unroll
    for (int i = 0; i < 4; ++i)
        out[(long)(c0 + ty + i * 8) * R + r0 + tx] = f2bf(t[tx][ty + i * 8]);
}

// ---------------------------------------------------------------------------
extern "C" void kernel_launch(void* const* d_in, const int* in_sizes, int n_in,
                              void* d_out, int out_size, void* d_ws, size_t ws_size,
                              hipStream_t stream)
{
    const float* H_l      = (const float*)d_in[0];
    const float* H_a      = (const float*)d_in[1];
    const float* W_text   = (const float*)d_in[2];
    const float* b_text   = (const float*)d_in[3];
    const float* W_audio  = (const float*)d_in[4];
    const float* b_audio  = (const float*)d_in[5];
    const float* W_out    = (const float*)d_in[6];
    const float* b_out    = (const float*)d_in[7];
    const float* g1       = (const float*)d_in[8];
    const float* beta1    = (const float*)d_in[9];
    const float* g2       = (const float*)d_in[10];
    const float* beta2    = (const float*)d_in[11];
    const float* g_out    = (const float*)d_in[12];
    const float* beta_out = (const float*)d_in[13];
    (void)in_sizes; (void)n_in; (void)out_size;

    const int B = 16, L = 1024, S = 2048, DT = 1024, DA = 768, H = 1024;

    // ---------------- workspace layout (~245.5 MiB, heavy overlay) ---------
    char* ws = (char*)d_ws;
    const size_t SZ_HLB = (size_t)B * L * DT * 2;
    const size_t SZ_HAB = (size_t)B * S * DA * 2;
    const size_t O_A    = SZ_HLB + SZ_HAB;
    const size_t SZ_A   = (size_t)B * L * H * 2;
    const size_t O_C    = O_A + SZ_A;
    const size_t SZ_C   = (size_t)B * S * H * 2;
    const size_t O_D    = O_C + SZ_C;
    const size_t SZ_D   = (size_t)B * S * H * 2;
    const size_t O_W    = O_D + SZ_D;
    const size_t need   = O_W + (size_t)(DT * H + DA * H + H * H) * 2;

    if (ws_size < need) {
        fprintf(stderr, "[kernel_launch] ws_size=%zu < needed=%zu — aborting launches\n",
                ws_size, need);
        return;
    }

    u16*   Hlb     = (u16*)(ws);
    u16*   Hab     = (u16*)(ws + SZ_HLB);
    u16*   Scores  = (u16*)(ws);                 // overlays Hlb/Hab after G2
    u16*   Abuf    = (u16*)(ws + O_A);           // text_p -> Q -> Hh
    u16*   Vbuf    = (u16*)(ws + O_C);           // audio_p (LN2 input)
    u16*   Kbuf    = (u16*)(ws + O_D);           // K
    u16*   OutPre  = (u16*)(ws + O_D);           // out_pre bf16 (after K dies)
    u16*   Wt_text  = (u16*)(ws + O_W);
    u16*   Wt_audio = Wt_text + (size_t)DT * H;
    u16*   Wt_out   = Wt_audio + (size_t)DA * H;
    u16*   Vt      = (u16*)d_out;                // dies before final LN

    const float scale = 0.03125f; // 1/sqrt(1024)

    // input casts to bf16
    cast_f32_bf16<<<(B * L * DT / 8 + 255) / 256, 256, 0, stream>>>(H_l, Hlb, (long)B * L * DT / 8);
    cast_f32_bf16<<<(B * S * DA / 8 + 255) / 256, 256, 0, stream>>>(H_a, Hab, (long)B * S * DA / 8);
    // weight transposes [K,N] -> [N,K] bf16
    tcast_f32_bf16<<<dim3(H / 32, DT / 32), dim3(32, 8), 0, stream>>>(W_text, Wt_text, DT, H);
    tcast_f32_bf16<<<dim3(H / 32, DA / 32), dim3(32, 8), 0, stream>>>(W_audio, Wt_audio, DA, H);
    tcast_f32_bf16<<<dim3(H / 32, H / 32),  dim3(32, 8), 0, stream>>>(W_out, Wt_out, H, H);

    // G1: text_p = H_l @ W_text + b_text   [16384,1024] bf16
    gemm_nt<1, true, false, true, false><<<dim3(H / 256, B * L / 256, 1), 512, 0, stream>>>(
        Hlb, Wt_text, Abuf, b_text, nullptr, nullptr, DT, DT, DT, H, 0, 0, 0, 1.0f);
    // LN1 in-place: text_p -> Q
    ln1024<true, true><<<B * L, 256, 0, stream>>>(Abuf, g1, beta1, Abuf);

    // G2: audio_p = H_a @ W_audio + b_audio [32768,1024] bf16 (= V),
    //     epilogue also writes V^T into Vt (d_out) -> no transpose kernel
    gemm_nt<2, true, false, true, true><<<dim3(H / 256, B * S / 256, 1), 512, 0, stream>>>(
        Hab, Wt_audio, Vbuf, b_audio, nullptr, Vt, DA, DA, DA, H, 0, 0, 0, 1.0f);
    // LN2: audio_p -> K
    ln1024<true, true><<<B * S, 256, 0, stream>>>(Vbuf, g2, beta2, Kbuf);

    // G3: scores = Q @ K^T * scale          [B,1024,2048] bf16
    gemm_nt<3, false, false, true, false><<<dim3(S / 256, L / 256, B), 512, 0, stream>>>(
        Abuf, Kbuf, Scores, nullptr, nullptr, nullptr, H, H, H, S,
        (long)L * H, (long)S * H, (long)L * S, scale);

    // softmax in-place on bf16 scores -> alpha
    softmax2048_bf16<<<B * L, 256, 0, stream>>>(Scores);

    // G5: H_hyper = alpha @ V (NT vs Vt)    [B,1024,1024] bf16 -> Abuf (Q dead)
    gemm_nt<5, false, false, true, false><<<dim3(H / 256, L / 256, B), 512, 0, stream>>>(
        Scores, Vt, Abuf, nullptr, nullptr, nullptr, S, S, S, H,
        (long)L * S, (long)H * S, (long)L * H, 1.0f);

    // G6: out_pre = H_hyper @ W_out + b_out + H_l  [16384,1024] bf16 (K dead)
    gemm_nt<6, true, true, true, false><<<dim3(H / 256, B * L / 256, 1), 512, 0, stream>>>(
        Abuf, Wt_out, OutPre, b_out, H_l, nullptr, H, H, H, H, 0, 0, 0, 1.0f);

    // LN3 (bf16 in) -> d_out fp32 (Vt dead)
    ln1024<true, false><<<B * L, 256, 0, stream>>>(OutPre, g_out, beta_out, (float*)d_out);
}

// Round 13
// 475.746 us; speedup vs baseline: 1.2509x; 1.0015x over previous
//
#include <hip/hip_runtime.h>
#include <cstdio>

typedef unsigned short u16;
typedef __bf16 bf16x8 __attribute__((ext_vector_type(8)));
typedef float f32x4 __attribute__((ext_vector_type(4)));
typedef unsigned short us4 __attribute__((ext_vector_type(4)));
typedef unsigned short us8 __attribute__((ext_vector_type(8)));

__device__ __forceinline__ u16 f2bf(float f) {
    union { float f; unsigned u; } x; x.f = f;
    unsigned u = x.u + 0x7fffu + ((x.u >> 16) & 1u);   // RNE
    return (u16)(u >> 16);
}
__device__ __forceinline__ float bf2f(u16 u) {
    union { unsigned u; float f; } x; x.u = ((unsigned)u) << 16;
    return x.f;
}

// ---------------------------------------------------------------------------
// NT GEMM: C[M,N] = A[M,K] * B[N,K]^T, bf16 in, fp32 accumulate.
// 256x256 tile, BK=64, 512 threads (8 waves 2Mx4N, 128x64 per wave).
// m201-faithful 4-phase/K-tile schedule, 4-slot HALF-TILE RING per operand
// (slot(tile T, half h) = (2T+h)&3; tile T+2 reuses tile T's slots):
//   p1: ds_read af0+bfr0 ; BAR ; lgkm0 ; prio1 ; 16 MFMA Q00 ; prio0 ; BAR
//   p2: ds_read bfr1     ; BAR ; lgkm0 ; prio1 ; 16 MFMA Q01 ; prio0 ; BAR
//   p3: ds_read af1 ; stage B(T+2) ; BAR ; lgkm0 ; prio1 ; Q10 ; prio0 ; BAR
//   p4: stage A(T+2)                ; prio1 ; Q11 (reg-only) ; prio0
//   iter top: counted vmcnt ; BAR   (serves as p4's trailing barrier)
// The lgkmcnt(0) after each lead barrier makes the MFMA cluster PURE:
// reads drain during the barrier wait (issued before it), the wait is ~free,
// and setprio then wraps an uninterrupted MFMA block (T5's precondition,
// m218b: +21-25% only with a clean cluster). NO sched_barrier (m141 tax).
// Counted vmcnt at iter top: vmcnt(8) = prev iter's 8 loads stay in flight;
// everything older (tile T's data) landed. Tail iter: vmcnt(0).
// Hazard ledger:
//   RAW global->LDS: own-wave vmcnt at iter top + top barrier -> all waves'
//     tile-T loads landed before any ds_read of T.
//   WAR (ring): B slots of tile T last read p2 (drained by p2's lgkm0 before
//     its trailing barrier) -> staged p3. A slots last read p3 -> staged p4.
//   RAW LDS->MFMA: lgkmcnt(0) + compiler-tracked deps (plain C++ loads).
// LDS: 2 x 64 KiB, XOR-swizzled rows (phys_koff = koff ^ ((row&7)<<4));
// stage pre-swizzles the GLOBAL source (both-sides rule). Conflicts = 0 (R12).
// EMIT_VT (G2 only): epilogue additionally writes V^T[b][n][s].
// grid: (N/256, M/256, batch) flattened; nwg % 8 == 0 for the XCD remap.
// Requires nt >= 3 (smallest K here is 768 -> nt=12).
// ---------------------------------------------------------------------------

#define LDFRAG(base, row, koff) \
  (*(const bf16x8*)((const char*)(base) + (size_t)(row) * 128 + \
                    ((koff) ^ (((row) & 7) << 4))))

#define BAR() do { \
  asm volatile("" ::: "memory"); \
  __builtin_amdgcn_s_barrier(); \
  asm volatile("" ::: "memory"); \
} while (0)

#define LGKM0() asm volatile("s_waitcnt lgkmcnt(0)" ::: "memory")

#define MFMA16(AF, BF, MO, NO) do { \
  __builtin_amdgcn_s_setprio(1); \
  _Pragma("unroll") for (int j = 0; j < 4; ++j) \
    _Pragma("unroll") for (int i = 0; i < 2; ++i) \
      _Pragma("unroll") for (int ks = 0; ks < 2; ++ks) \
        acc[(MO) + j][(NO) + i] = __builtin_amdgcn_mfma_f32_16x16x32_bf16( \
            AF[j][ks], BF[i][ks], acc[(MO) + j][(NO) + i], 0, 0, 0); \
  __builtin_amdgcn_s_setprio(0); \
} while (0)

template<int TAG, bool HAS_BIAS, bool HAS_RESID, bool OUT_BF16, bool EMIT_VT>
__global__ __launch_bounds__(512, 2)
void gemm_nt(const u16* __restrict__ A, const u16* __restrict__ Bm,
             void* __restrict__ Cm, const float* __restrict__ bias,
             const float* __restrict__ resid, u16* __restrict__ vt,
             int K, int lda, int ldb, int ldc,
             long sA, long sB, long sC, float scale)
{
    // 4 half-tile slots per operand, 8192 u16 (16 KB) each; rows 128B swz.
    __shared__ __align__(16) u16 lA[4 * 128 * 64];   // 64 KiB
    __shared__ __align__(16) u16 lB[4 * 128 * 64];   // 64 KiB

    const int tid = threadIdx.x;

    // ---- bijective XCD chunking over the flattened 3D grid (nwg%8==0) ----
    const int gx = gridDim.x, gy = gridDim.y;
    int flat = ((int)blockIdx.z * gy + blockIdx.y) * gx + blockIdx.x;
    const int nwg = gx * gy * (int)gridDim.z;
    const int q = nwg >> 3;
    flat = (flat & 7) * q + (flat >> 3);
    const int bx = flat % gx;
    const int t2 = flat / gx;
    const int by = t2 % gy;
    const long bz = t2 / gy;

    A  += bz * sA;
    Bm += bz * sB;
    const long cbase = bz * sC;
    const int m0 = by * 256;
    const int n0 = bx * 256;

    const int lane = tid & 63;
    const int w  = tid >> 6;                  // wave 0..7
    const int wr = w >> 2, wc = w & 3;        // 2x4 wave grid, 128x64 per wave
    const int fr = lane & 15;                 // A row / B col within fragment
    const int kg = lane >> 4;                 // k-group (0..3)

    // stage one half-tile (128 rows x 64 K = 16 KB) of operand op, half h,
    // K-tile kt, into ring slot (2*kt+h)&3. Global source pre-swizzled;
    // LDS dest linear. 2 global_load_lds per thread per call.
    auto stage_half = [&](int kt, int op, int h) {
        const u16* src = op ? Bm : A;
        const int  ld  = op ? ldb : lda;
        const int  bs  = op ? n0 : m0;
        u16* lds = (op ? lB : lA) + (size_t)(((2 * kt + h) & 3)) * 8192;
#pragma unroll
        for (int i2 = 0; i2 < 2; ++i2) {
            const int c  = i2 * 512 + tid;            // 16B chunk id, 0..1023
            const int r  = c >> 3;                    // row within half
            const int kb = ((c & 7) * 16) ^ ((r & 7) << 4);   // pre-swizzled k byte
            const u16* g = src + (size_t)(bs + h * 128 + r) * ld + kt * 64 + (kb >> 1);
            __builtin_amdgcn_global_load_lds(
                (const __attribute__((address_space(1))) void*)g,
                (__attribute__((address_space(3))) void*)(lds + (size_t)c * 8), 16, 0, 0);
        }
    };
    auto stage_tile = [&](int kt) {
        stage_half(kt, 0, 0); stage_half(kt, 0, 1);
        stage_half(kt, 1, 0); stage_half(kt, 1, 1);
    };

    f32x4 acc[8][4] = {};

    const int nt = K >> 6;                    // nt >= 12 for all GEMMs here
    stage_tile(0);                            // slots A/B 0,1
    stage_tile(1);                            // slots A/B 2,3

    const int bRowBase = (wc & 1) * 64;       // B local row base within slot

    for (int T = 0; T < nt; ++T) {
        // ---- iter top: tile T's staging landed (all waves) ----
        if (T == nt - 1) asm volatile("s_waitcnt vmcnt(0)" ::: "memory");
        else             asm volatile("s_waitcnt vmcnt(8)" ::: "memory");
        BAR();                                // also serves as p4's trailing bar

        const u16* pA = lA + (size_t)(((2 * T + wr) & 3)) * 8192;
        const u16* pB = lB + (size_t)(((2 * T + (wc >> 1)) & 3)) * 8192;
        const bool pre = (T + 2 < nt);

        bf16x8 af0[4][2], af1[4][2], bfr0[2][2], bfr1[2][2];

        // ---- phase 1: read af0 (rows 0-63 of wave half) + bfr0 ; Q00 ----
#pragma unroll
        for (int j = 0; j < 4; ++j)
#pragma unroll
            for (int ks = 0; ks < 2; ++ks)
                af0[j][ks] = LDFRAG(pA, j * 16 + fr, ks * 64 + kg * 16);
#pragma unroll
        for (int i = 0; i < 2; ++i)
#pragma unroll
            for (int ks = 0; ks < 2; ++ks)
                bfr0[i][ks] = LDFRAG(pB, bRowBase + i * 16 + fr, ks * 64 + kg * 16);
        BAR();
        LGKM0();
        MFMA16(af0, bfr0, 0, 0);
        BAR();

        // ---- phase 2: read bfr1 ; Q01 ----
#pragma unroll
        for (int i = 0; i < 2; ++i)
#pragma unroll
            for (int ks = 0; ks < 2; ++ks)
                bfr1[i][ks] = LDFRAG(pB, bRowBase + 32 + i * 16 + fr, ks * 64 + kg * 16);
        BAR();
        LGKM0();
        MFMA16(af0, bfr1, 0, 2);
        BAR();

        // ---- phase 3: read af1 (rows 64-127) ; stage B halves of T+2 ; Q10
        //      (B slots of tile T were last read in p2 -> free now)
#pragma unroll
        for (int j = 0; j < 4; ++j)
#pragma unroll
            for (int ks = 0; ks < 2; ++ks)
                af1[j][ks] = LDFRAG(pA, 64 + j * 16 + fr, ks * 64 + kg * 16);
        if (pre) { stage_half(T + 2, 1, 0); stage_half(T + 2, 1, 1); }
        BAR();
        LGKM0();
        MFMA16(af1, bfr0, 4, 0);
        BAR();

        // ---- phase 4: stage A halves of T+2 ; Q11 (register-only MFMA)
        //      (A slots of tile T were last read in p3 -> free now)
        if (pre) { stage_half(T + 2, 0, 0); stage_half(T + 2, 0, 1); }
        MFMA16(af1, bfr1, 4, 2);
        // trailing barrier merged into next iter-top BAR
    }

    // epilogue: C/D layout col=lane&15, row=(lane>>4)*4+reg  [m89-verified]
    const int orow = m0 + wr * 128 + kg * 4;
    const int ocol = n0 + wc * 64 + fr;
#pragma unroll
    for (int mf = 0; mf < 8; ++mf) {
        const int mbase = orow + mf * 16;     // 4 consecutive rows mbase..+3
#pragma unroll
        for (int nf = 0; nf < 4; ++nf) {
            const int n = ocol + nf * 16;
            float v4[4];
#pragma unroll
            for (int r = 0; r < 4; ++r) {
                const int m = mbase + r;
                float v = acc[mf][nf][r] * scale;
                if (HAS_BIAS)  v += bias[n];
                if (HAS_RESID) v += resid[cbase + (long)m * ldc + n];
                v4[r] = v;
                if (OUT_BF16)  ((u16*)Cm)[cbase + (long)m * ldc + n] = f2bf(v);
                else           ((float*)Cm)[cbase + (long)m * ldc + n] = v;
            }
            if (EMIT_VT) {
                // rows m = b*2048 + s; write Vt[b][n][s..s+3] (batch S=2048)
                const long b_ = mbase >> 11;
                const int  s  = mbase & 2047;
                us4 o;
#pragma unroll
                for (int r = 0; r < 4; ++r) o[r] = f2bf(v4[r]);
                *(us4*)(vt + (b_ * 1024 + n) * 2048 + s) = o;
            }
        }
    }
}

// ---------------------------------------------------------------------------
// LayerNorm over D=1024, one block (256 thr) per row.
// ---------------------------------------------------------------------------
template<bool IN_BF16, bool OUT_BF16>
__global__ __launch_bounds__(256)
void ln1024(const void* in, const float* __restrict__ g,
            const float* __restrict__ beta, void* out)
{
    const long row = blockIdx.x;
    const int tid = threadIdx.x;
    float x0, x1, x2, x3;
    if (IN_BF16) {
        const us4 v = ((const us4*)in)[row * 256 + tid];
        x0 = bf2f(v[0]); x1 = bf2f(v[1]); x2 = bf2f(v[2]); x3 = bf2f(v[3]);
    } else {
        const float4 v = ((const float4*)in)[row * 256 + tid];
        x0 = v.x; x1 = v.y; x2 = v.z; x3 = v.w;
    }
    float s  = x0 + x1 + x2 + x3;
    float s2 = x0 * x0 + x1 * x1 + x2 * x2 + x3 * x3;
#pragma unroll
    for (int off = 32; off > 0; off >>= 1) {
        s  += __shfl_xor(s, off);
        s2 += __shfl_xor(s2, off);
    }
    __shared__ float rs[4], rq[4];
    if ((tid & 63) == 0) { rs[tid >> 6] = s; rq[tid >> 6] = s2; }
    __syncthreads();
    const float S  = rs[0] + rs[1] + rs[2] + rs[3];
    const float S2 = rq[0] + rq[1] + rq[2] + rq[3];
    const float mu = S * (1.0f / 1024.0f);
    const float var = S2 * (1.0f / 1024.0f) - mu * mu;
    const float rstd = rsqrtf(var + 1e-5f);
    const float4 gg = ((const float4*)g)[tid];
    const float4 bb = ((const float4*)beta)[tid];
    const float y0 = (x0 - mu) * rstd * gg.x + bb.x;
    const float y1 = (x1 - mu) * rstd * gg.y + bb.y;
    const float y2 = (x2 - mu) * rstd * gg.z + bb.z;
    const float y3 = (x3 - mu) * rstd * gg.w + bb.w;
    if (OUT_BF16) {
        us4 o; o[0] = f2bf(y0); o[1] = f2bf(y1); o[2] = f2bf(y2); o[3] = f2bf(y3);
        ((us4*)out)[row * 256 + tid] = o;
    } else {
        float4 o; o.x = y0; o.y = y1; o.z = y2; o.w = y3;
        ((float4*)out)[row * 256 + tid] = o;
    }
}

// ---------------------------------------------------------------------------
// Softmax over width 2048, bf16 in/out, IN-PLACE. One block per row.
// ---------------------------------------------------------------------------
__global__ __launch_bounds__(256)
void softmax2048_bf16(u16* io)
{
    const long row = blockIdx.x;
    const int tid = threadIdx.x;
    const us8 v = ((const us8*)io)[row * 256 + tid];
    float x[8];
#pragma unroll
    for (int i = 0; i < 8; ++i) x[i] = bf2f(v[i]);
    float m = x[0];
#pragma unroll
    for (int i = 1; i < 8; ++i) m = fmaxf(m, x[i]);
#pragma unroll
    for (int off = 32; off > 0; off >>= 1) m = fmaxf(m, __shfl_xor(m, off));
    __shared__ float rm[4], rsum[4];
    if ((tid & 63) == 0) rm[tid >> 6] = m;
    __syncthreads();
    m = fmaxf(fmaxf(rm[0], rm[1]), fmaxf(rm[2], rm[3]));
    float e[8];
    float s = 0.f;
#pragma unroll
    for (int i = 0; i < 8; ++i) { e[i] = __expf(x[i] - m); s += e[i]; }
#pragma unroll
    for (int off = 32; off > 0; off >>= 1) s += __shfl_xor(s, off);
    if ((tid & 63) == 0) rsum[tid >> 6] = s;
    __syncthreads();
    s = rsum[0] + rsum[1] + rsum[2] + rsum[3];
    const float inv = 1.0f / s;
    us8 o;
#pragma unroll
    for (int i = 0; i < 8; ++i) o[i] = f2bf(e[i] * inv);
    ((us8*)io)[row * 256 + tid] = o;
}

// fp32 -> bf16 cast, 8 elems/thread
__global__ __launch_bounds__(256)
void cast_f32_bf16(const float* __restrict__ in, u16* __restrict__ out, long n8)
{
    const long i = (long)blockIdx.x * 256 + threadIdx.x;
    if (i >= n8) return;
    const float4 a = ((const float4*)in)[i * 2];
    const float4 b = ((const float4*)in)[i * 2 + 1];
    us8 o;
    o[0] = f2bf(a.x); o[1] = f2bf(a.y); o[2] = f2bf(a.z); o[3] = f2bf(a.w);
    o[4] = f2bf(b.x); o[5] = f2bf(b.y); o[6] = f2bf(b.z); o[7] = f2bf(b.w);
    ((us8*)out)[i] = o;
}

// transpose + cast: fp32 [R,C] -> bf16 [C,R]. block (32,8), grid (C/32, R/32)
__global__ __launch_bounds__(256)
void tcast_f32_bf16(const float* __restrict__ in, u16* __restrict__ out,
                    int R, int C)
{
    __shared__ float t[32][33];
    const int tx = threadIdx.x, ty = threadIdx.y;
    const int c0 = blockIdx.x * 32, r0 = blockIdx.y * 32;
#pragma unroll
    for (int i = 0; i < 4; ++i)
        t[ty + i * 8][tx] = in[(long)(r0 + ty + i * 8) * C + c0 + tx];
    __syncthreads();
#pragma unroll
    for (int i = 0; i < 4; ++i)
        out[(long)(c0 + ty + i * 8) * R + r0 + tx] = f2bf(t[tx][ty + i * 8]);
}

// ---------------------------------------------------------------------------
extern "C" void kernel_launch(void* const* d_in, const int* in_sizes, int n_in,
                              void* d_out, int out_size, void* d_ws, size_t ws_size,
                              hipStream_t stream)
{
    const float* H_l      = (const float*)d_in[0];
    const float* H_a      = (const float*)d_in[1];
    const float* W_text   = (const float*)d_in[2];
    const float* b_text   = (const float*)d_in[3];
    const float* W_audio  = (const float*)d_in[4];
    const float* b_audio  = (const float*)d_in[5];
    const float* W_out    = (const float*)d_in[6];
    const float* b_out    = (const float*)d_in[7];
    const float* g1       = (const float*)d_in[8];
    const float* beta1    = (const float*)d_in[9];
    const float* g2       = (const float*)d_in[10];
    const float* beta2    = (const float*)d_in[11];
    const float* g_out    = (const float*)d_in[12];
    const float* beta_out = (const float*)d_in[13];
    (void)in_sizes; (void)n_in; (void)out_size;

    const int B = 16, L = 1024, S = 2048, DT = 1024, DA = 768, H = 1024;

    // ---------------- workspace layout (~245.5 MiB, heavy overlay) ---------
    char* ws = (char*)d_ws;
    const size_t SZ_HLB = (size_t)B * L * DT * 2;
    const size_t SZ_HAB = (size_t)B * S * DA * 2;
    const size_t O_A    = SZ_HLB + SZ_HAB;
    const size_t SZ_A   = (size_t)B * L * H * 2;
    const size_t O_C    = O_A + SZ_A;
    const size_t SZ_C   = (size_t)B * S * H * 2;
    const size_t O_D    = O_C + SZ_C;
    const size_t SZ_D   = (size_t)B * S * H * 2;
    const size_t O_W    = O_D + SZ_D;
    const size_t need   = O_W + (size_t)(DT * H + DA * H + H * H) * 2;

    if (ws_size < need) {
        fprintf(stderr, "[kernel_launch] ws_size=%zu < needed=%zu — aborting launches\n",
                ws_size, need);
        return;
    }

    u16*   Hlb     = (u16*)(ws);
    u16*   Hab     = (u16*)(ws + SZ_HLB);
    u16*   Scores  = (u16*)(ws);                 // overlays Hlb/Hab after G2
    u16*   Abuf    = (u16*)(ws + O_A);           // text_p -> Q -> Hh
    u16*   Vbuf    = (u16*)(ws + O_C);           // audio_p (LN2 input)
    u16*   Kbuf    = (u16*)(ws + O_D);           // K
    u16*   OutPre  = (u16*)(ws + O_D);           // out_pre bf16 (after K dies)
    u16*   Wt_text  = (u16*)(ws + O_W);
    u16*   Wt_audio = Wt_text + (size_t)DT * H;
    u16*   Wt_out   = Wt_audio + (size_t)DA * H;
    u16*   Vt      = (u16*)d_out;                // dies before final LN

    const float scale = 0.03125f; // 1/sqrt(1024)

    // input casts to bf16
    cast_f32_bf16<<<(B * L * DT / 8 + 255) / 256, 256, 0, stream>>>(H_l, Hlb, (long)B * L * DT / 8);
    cast_f32_bf16<<<(B * S * DA / 8 + 255) / 256, 256, 0, stream>>>(H_a, Hab, (long)B * S * DA / 8);
    // weight transposes [K,N] -> [N,K] bf16
    tcast_f32_bf16<<<dim3(H / 32, DT / 32), dim3(32, 8), 0, stream>>>(W_text, Wt_text, DT, H);
    tcast_f32_bf16<<<dim3(H / 32, DA / 32), dim3(32, 8), 0, stream>>>(W_audio, Wt_audio, DA, H);
    tcast_f32_bf16<<<dim3(H / 32, H / 32),  dim3(32, 8), 0, stream>>>(W_out, Wt_out, H, H);

    // G1: text_p = H_l @ W_text + b_text   [16384,1024] bf16
    gemm_nt<1, true, false, true, false><<<dim3(H / 256, B * L / 256, 1), 512, 0, stream>>>(
        Hlb, Wt_text, Abuf, b_text, nullptr, nullptr, DT, DT, DT, H, 0, 0, 0, 1.0f);
    // LN1 in-place: text_p -> Q
    ln1024<true, true><<<B * L, 256, 0, stream>>>(Abuf, g1, beta1, Abuf);

    // G2: audio_p = H_a @ W_audio + b_audio [32768,1024] bf16 (= V),
    //     epilogue also writes V^T into Vt (d_out) -> no transpose kernel
    gemm_nt<2, true, false, true, true><<<dim3(H / 256, B * S / 256, 1), 512, 0, stream>>>(
        Hab, Wt_audio, Vbuf, b_audio, nullptr, Vt, DA, DA, DA, H, 0, 0, 0, 1.0f);
    // LN2: audio_p -> K
    ln1024<true, true><<<B * S, 256, 0, stream>>>(Vbuf, g2, beta2, Kbuf);

    // G3: scores = Q @ K^T * scale          [B,1024,2048] bf16
    gemm_nt<3, false, false, true, false><<<dim3(S / 256, L / 256, B), 512, 0, stream>>>(
        Abuf, Kbuf, Scores, nullptr, nullptr, nullptr, H, H, H, S,
        (long)L * H, (long)S * H, (long)L * S, scale);

    // softmax in-place on bf16 scores -> alpha
    softmax2048_bf16<<<B * L, 256, 0, stream>>>(Scores);

    // G5: H_hyper = alpha @ V (NT vs Vt)    [B,1024,1024] bf16 -> Abuf (Q dead)
    gemm_nt<5, false, false, true, false><<<dim3(H / 256, L / 256, B), 512, 0, stream>>>(
        Scores, Vt, Abuf, nullptr, nullptr, nullptr, S, S, S, H,
        (long)L * S, (long)H * S, (long)L * H, 1.0f);

    // G6: out_pre = H_hyper @ W_out + b_out + H_l  [16384,1024] bf16 (K dead)
    gemm_nt<6, true, true, true, false><<<dim3(H / 256, B * L / 256, 1), 512, 0, stream>>>(
        Abuf, Wt_out, OutPre, b_out, H_l, nullptr, H, H, H, H, 0, 0, 0, 1.0f);

    // LN3 (bf16 in) -> d_out fp32 (Vt dead)
    ln1024<true, false><<<B * L, 256, 0, stream>>>(OutPre, g_out, beta_out, (float*)d_out);
}

// Round 14
// 473.254 us; speedup vs baseline: 1.2575x; 1.0053x over previous
//
#include <hip/hip_runtime.h>
#include <cstdio>

typedef unsigned short u16;
typedef __bf16 bf16x8 __attribute__((ext_vector_type(8)));
typedef float f32x4 __attribute__((ext_vector_type(4)));
typedef unsigned short us4 __attribute__((ext_vector_type(4)));
typedef unsigned short us8 __attribute__((ext_vector_type(8)));

__device__ __forceinline__ u16 f2bf(float f) {
    union { float f; unsigned u; } x; x.f = f;
    unsigned u = x.u + 0x7fffu + ((x.u >> 16) & 1u);   // RNE
    return (u16)(u >> 16);
}
__device__ __forceinline__ float bf2f(u16 u) {
    union { unsigned u; float f; } x; x.u = ((unsigned)u) << 16;
    return x.f;
}

// ---------------------------------------------------------------------------
// NT GEMM: C[M,N] = A[M,K] * B[N,K]^T, bf16 in, fp32 accumulate.
// 256x256 tile, BK=64, 512 threads (8 waves 2Mx4N, 128x64 per wave).
// R13 kernel, UNCHANGED (475.7 us verified): 4-phase/K-tile, 4-slot
// half-tile ring per operand (slot(T,h) = (2T+h)&3), counted vmcnt(8) at
// iter top, lgkmcnt(0)-pure MFMA clusters wrapped in setprio, no
// sched_barrier. Hazard ledger as R12/R13 (see comments inline).
// ---------------------------------------------------------------------------

#define LDFRAG(base, row, koff) \
  (*(const bf16x8*)((const char*)(base) + (size_t)(row) * 128 + \
                    ((koff) ^ (((row) & 7) << 4))))

#define BAR() do { \
  asm volatile("" ::: "memory"); \
  __builtin_amdgcn_s_barrier(); \
  asm volatile("" ::: "memory"); \
} while (0)

#define LGKM0() asm volatile("s_waitcnt lgkmcnt(0)" ::: "memory")

#define MFMA16(AF, BF, MO, NO) do { \
  __builtin_amdgcn_s_setprio(1); \
  _Pragma("unroll") for (int j = 0; j < 4; ++j) \
    _Pragma("unroll") for (int i = 0; i < 2; ++i) \
      _Pragma("unroll") for (int ks = 0; ks < 2; ++ks) \
        acc[(MO) + j][(NO) + i] = __builtin_amdgcn_mfma_f32_16x16x32_bf16( \
            AF[j][ks], BF[i][ks], acc[(MO) + j][(NO) + i], 0, 0, 0); \
  __builtin_amdgcn_s_setprio(0); \
} while (0)

template<int TAG, bool HAS_BIAS, bool HAS_RESID, bool OUT_BF16, bool EMIT_VT>
__global__ __launch_bounds__(512, 2)
void gemm_nt(const u16* __restrict__ A, const u16* __restrict__ Bm,
             void* __restrict__ Cm, const float* __restrict__ bias,
             const float* __restrict__ resid, u16* __restrict__ vt,
             int K, int lda, int ldb, int ldc,
             long sA, long sB, long sC, float scale)
{
    // 4 half-tile slots per operand, 8192 u16 (16 KB) each; rows 128B swz.
    __shared__ __align__(16) u16 lA[4 * 128 * 64];   // 64 KiB
    __shared__ __align__(16) u16 lB[4 * 128 * 64];   // 64 KiB

    const int tid = threadIdx.x;

    // ---- bijective XCD chunking over the flattened 3D grid (nwg%8==0) ----
    const int gx = gridDim.x, gy = gridDim.y;
    int flat = ((int)blockIdx.z * gy + blockIdx.y) * gx + blockIdx.x;
    const int nwg = gx * gy * (int)gridDim.z;
    const int q = nwg >> 3;
    flat = (flat & 7) * q + (flat >> 3);
    const int bx = flat % gx;
    const int t2 = flat / gx;
    const int by = t2 % gy;
    const long bz = t2 / gy;

    A  += bz * sA;
    Bm += bz * sB;
    const long cbase = bz * sC;
    const int m0 = by * 256;
    const int n0 = bx * 256;

    const int lane = tid & 63;
    const int w  = tid >> 6;                  // wave 0..7
    const int wr = w >> 2, wc = w & 3;        // 2x4 wave grid, 128x64 per wave
    const int fr = lane & 15;                 // A row / B col within fragment
    const int kg = lane >> 4;                 // k-group (0..3)

    // stage one half-tile (128 rows x 64 K = 16 KB) of operand op, half h,
    // K-tile kt, into ring slot (2*kt+h)&3. Global source pre-swizzled;
    // LDS dest linear. 2 global_load_lds per thread per call.
    auto stage_half = [&](int kt, int op, int h) {
        const u16* src = op ? Bm : A;
        const int  ld  = op ? ldb : lda;
        const int  bs  = op ? n0 : m0;
        u16* lds = (op ? lB : lA) + (size_t)(((2 * kt + h) & 3)) * 8192;
#pragma unroll
        for (int i2 = 0; i2 < 2; ++i2) {
            const int c  = i2 * 512 + tid;            // 16B chunk id, 0..1023
            const int r  = c >> 3;                    // row within half
            const int kb = ((c & 7) * 16) ^ ((r & 7) << 4);   // pre-swizzled k byte
            const u16* g = src + (size_t)(bs + h * 128 + r) * ld + kt * 64 + (kb >> 1);
            __builtin_amdgcn_global_load_lds(
                (const __attribute__((address_space(1))) void*)g,
                (__attribute__((address_space(3))) void*)(lds + (size_t)c * 8), 16, 0, 0);
        }
    };
    auto stage_tile = [&](int kt) {
        stage_half(kt, 0, 0); stage_half(kt, 0, 1);
        stage_half(kt, 1, 0); stage_half(kt, 1, 1);
    };

    f32x4 acc[8][4] = {};

    const int nt = K >> 6;                    // nt >= 12 for all GEMMs here
    stage_tile(0);                            // slots A/B 0,1
    stage_tile(1);                            // slots A/B 2,3

    const int bRowBase = (wc & 1) * 64;       // B local row base within slot

    for (int T = 0; T < nt; ++T) {
        // ---- iter top: tile T's staging landed (all waves) ----
        if (T == nt - 1) asm volatile("s_waitcnt vmcnt(0)" ::: "memory");
        else             asm volatile("s_waitcnt vmcnt(8)" ::: "memory");
        BAR();                                // also serves as p4's trailing bar

        const u16* pA = lA + (size_t)(((2 * T + wr) & 3)) * 8192;
        const u16* pB = lB + (size_t)(((2 * T + (wc >> 1)) & 3)) * 8192;
        const bool pre = (T + 2 < nt);

        bf16x8 af0[4][2], af1[4][2], bfr0[2][2], bfr1[2][2];

        // ---- phase 1: read af0 (rows 0-63 of wave half) + bfr0 ; Q00 ----
#pragma unroll
        for (int j = 0; j < 4; ++j)
#pragma unroll
            for (int ks = 0; ks < 2; ++ks)
                af0[j][ks] = LDFRAG(pA, j * 16 + fr, ks * 64 + kg * 16);
#pragma unroll
        for (int i = 0; i < 2; ++i)
#pragma unroll
            for (int ks = 0; ks < 2; ++ks)
                bfr0[i][ks] = LDFRAG(pB, bRowBase + i * 16 + fr, ks * 64 + kg * 16);
        BAR();
        LGKM0();
        MFMA16(af0, bfr0, 0, 0);
        BAR();

        // ---- phase 2: read bfr1 ; Q01 ----
#pragma unroll
        for (int i = 0; i < 2; ++i)
#pragma unroll
            for (int ks = 0; ks < 2; ++ks)
                bfr1[i][ks] = LDFRAG(pB, bRowBase + 32 + i * 16 + fr, ks * 64 + kg * 16);
        BAR();
        LGKM0();
        MFMA16(af0, bfr1, 0, 2);
        BAR();

        // ---- phase 3: read af1 (rows 64-127) ; stage B halves of T+2 ; Q10
        //      (B slots of tile T were last read in p2 -> free now)
#pragma unroll
        for (int j = 0; j < 4; ++j)
#pragma unroll
            for (int ks = 0; ks < 2; ++ks)
                af1[j][ks] = LDFRAG(pA, 64 + j * 16 + fr, ks * 64 + kg * 16);
        if (pre) { stage_half(T + 2, 1, 0); stage_half(T + 2, 1, 1); }
        BAR();
        LGKM0();
        MFMA16(af1, bfr0, 4, 0);
        BAR();

        // ---- phase 4: stage A halves of T+2 ; Q11 (register-only MFMA)
        //      (A slots of tile T were last read in p3 -> free now)
        if (pre) { stage_half(T + 2, 0, 0); stage_half(T + 2, 0, 1); }
        MFMA16(af1, bfr1, 4, 2);
        // trailing barrier merged into next iter-top BAR
    }

    // epilogue: C/D layout col=lane&15, row=(lane>>4)*4+reg  [m89-verified]
    const int orow = m0 + wr * 128 + kg * 4;
    const int ocol = n0 + wc * 64 + fr;
#pragma unroll
    for (int mf = 0; mf < 8; ++mf) {
        const int mbase = orow + mf * 16;     // 4 consecutive rows mbase..+3
#pragma unroll
        for (int nf = 0; nf < 4; ++nf) {
            const int n = ocol + nf * 16;
            float v4[4];
#pragma unroll
            for (int r = 0; r < 4; ++r) {
                const int m = mbase + r;
                float v = acc[mf][nf][r] * scale;
                if (HAS_BIAS)  v += bias[n];
                if (HAS_RESID) v += resid[cbase + (long)m * ldc + n];
                v4[r] = v;
                if (OUT_BF16)  ((u16*)Cm)[cbase + (long)m * ldc + n] = f2bf(v);
                else           ((float*)Cm)[cbase + (long)m * ldc + n] = v;
            }
            if (EMIT_VT) {
                // rows m = b*2048 + s; write Vt[b][n][s..s+3] (batch S=2048)
                const long b_ = mbase >> 11;
                const int  s  = mbase & 2047;
                us4 o;
#pragma unroll
                for (int r = 0; r < 4; ++r) o[r] = f2bf(v4[r]);
                *(us4*)(vt + (b_ * 1024 + n) * 2048 + s) = o;
            }
        }
    }
}

// ---------------------------------------------------------------------------
// LayerNorm over D=1024, one block (256 thr) per row.
// ---------------------------------------------------------------------------
template<bool IN_BF16, bool OUT_BF16>
__global__ __launch_bounds__(256)
void ln1024(const void* in, const float* __restrict__ g,
            const float* __restrict__ beta, void* out)
{
    const long row = blockIdx.x;
    const int tid = threadIdx.x;
    float x0, x1, x2, x3;
    if (IN_BF16) {
        const us4 v = ((const us4*)in)[row * 256 + tid];
        x0 = bf2f(v[0]); x1 = bf2f(v[1]); x2 = bf2f(v[2]); x3 = bf2f(v[3]);
    } else {
        const float4 v = ((const float4*)in)[row * 256 + tid];
        x0 = v.x; x1 = v.y; x2 = v.z; x3 = v.w;
    }
    float s  = x0 + x1 + x2 + x3;
    float s2 = x0 * x0 + x1 * x1 + x2 * x2 + x3 * x3;
#pragma unroll
    for (int off = 32; off > 0; off >>= 1) {
        s  += __shfl_xor(s, off);
        s2 += __shfl_xor(s2, off);
    }
    __shared__ float rs[4], rq[4];
    if ((tid & 63) == 0) { rs[tid >> 6] = s; rq[tid >> 6] = s2; }
    __syncthreads();
    const float S  = rs[0] + rs[1] + rs[2] + rs[3];
    const float S2 = rq[0] + rq[1] + rq[2] + rq[3];
    const float mu = S * (1.0f / 1024.0f);
    const float var = S2 * (1.0f / 1024.0f) - mu * mu;
    const float rstd = rsqrtf(var + 1e-5f);
    const float4 gg = ((const float4*)g)[tid];
    const float4 bb = ((const float4*)beta)[tid];
    const float y0 = (x0 - mu) * rstd * gg.x + bb.x;
    const float y1 = (x1 - mu) * rstd * gg.y + bb.y;
    const float y2 = (x2 - mu) * rstd * gg.z + bb.z;
    const float y3 = (x3 - mu) * rstd * gg.w + bb.w;
    if (OUT_BF16) {
        us4 o; o[0] = f2bf(y0); o[1] = f2bf(y1); o[2] = f2bf(y2); o[3] = f2bf(y3);
        ((us4*)out)[row * 256 + tid] = o;
    } else {
        float4 o; o.x = y0; o.y = y1; o.z = y2; o.w = y3;
        ((float4*)out)[row * 256 + tid] = o;
    }
}

// ---------------------------------------------------------------------------
// Softmax over width 2048, bf16 in/out, IN-PLACE. One block per row.
// ---------------------------------------------------------------------------
__global__ __launch_bounds__(256)
void softmax2048_bf16(u16* io)
{
    const long row = blockIdx.x;
    const int tid = threadIdx.x;
    const us8 v = ((const us8*)io)[row * 256 + tid];
    float x[8];
#pragma unroll
    for (int i = 0; i < 8; ++i) x[i] = bf2f(v[i]);
    float m = x[0];
#pragma unroll
    for (int i = 1; i < 8; ++i) m = fmaxf(m, x[i]);
#pragma unroll
    for (int off = 32; off > 0; off >>= 1) m = fmaxf(m, __shfl_xor(m, off));
    __shared__ float rm[4], rsum[4];
    if ((tid & 63) == 0) rm[tid >> 6] = m;
    __syncthreads();
    m = fmaxf(fmaxf(rm[0], rm[1]), fmaxf(rm[2], rm[3]));
    float e[8];
    float s = 0.f;
#pragma unroll
    for (int i = 0; i < 8; ++i) { e[i] = __expf(x[i] - m); s += e[i]; }
#pragma unroll
    for (int off = 32; off > 0; off >>= 1) s += __shfl_xor(s, off);
    if ((tid & 63) == 0) rsum[tid >> 6] = s;
    __syncthreads();
    s = rsum[0] + rsum[1] + rsum[2] + rsum[3];
    const float inv = 1.0f / s;
    us8 o;
#pragma unroll
    for (int i = 0; i < 8; ++i) o[i] = f2bf(e[i] * inv);
    ((us8*)io)[row * 256 + tid] = o;
}

// ---------------------------------------------------------------------------
// Merged input cast: fp32 -> bf16, 8 elems/thread, two sources in one grid.
// chunks [0, nA8) -> srcA/dstA ; [nA8, nA8+nB8) -> srcB/dstB.
// ---------------------------------------------------------------------------
__global__ __launch_bounds__(256)
void cast2_f32_bf16(const float* __restrict__ srcA, u16* __restrict__ dstA, long nA8,
                    const float* __restrict__ srcB, u16* __restrict__ dstB, long nB8)
{
    long i = (long)blockIdx.x * 256 + threadIdx.x;
    const float* in;
    u16* out;
    if (i < nA8) { in = srcA; out = dstA; }
    else         { i -= nA8; if (i >= nB8) return; in = srcB; out = dstB; }
    const float4 a = ((const float4*)in)[i * 2];
    const float4 b = ((const float4*)in)[i * 2 + 1];
    us8 o;
    o[0] = f2bf(a.x); o[1] = f2bf(a.y); o[2] = f2bf(a.z); o[3] = f2bf(a.w);
    o[4] = f2bf(b.x); o[5] = f2bf(b.y); o[6] = f2bf(b.z); o[7] = f2bf(b.w);
    ((us8*)out)[i] = o;
}

// ---------------------------------------------------------------------------
// Merged weight transpose+cast: fp32 [R,C] -> bf16 [C,R], 3 weights in one
// grid (z selects descriptor; row-guard for z==1 R=768). block (32,8).
// ---------------------------------------------------------------------------
__global__ __launch_bounds__(256)
void tcast3_f32_bf16(const float* __restrict__ w0, u16* __restrict__ t0,
                     const float* __restrict__ w1, u16* __restrict__ t1,
                     const float* __restrict__ w2, u16* __restrict__ t2)
{
    const int z = blockIdx.z;
    const float* in; u16* out; int R;
    if      (z == 0) { in = w0; out = t0; R = 1024; }
    else if (z == 1) { in = w1; out = t1; R = 768;  }
    else             { in = w2; out = t2; R = 1024; }
    const int C = 1024;
    const int r0 = blockIdx.y * 32;
    if (r0 >= R) return;
    __shared__ float t[32][33];
    const int tx = threadIdx.x, ty = threadIdx.y;
    const int c0 = blockIdx.x * 32;
#pragma unroll
    for (int i = 0; i < 4; ++i)
        t[ty + i * 8][tx] = in[(long)(r0 + ty + i * 8) * C + c0 + tx];
    __syncthreads();
#pragma unroll
    for (int i = 0; i < 4; ++i)
        out[(long)(c0 + ty + i * 8) * R + r0 + tx] = f2bf(t[tx][ty + i * 8]);
}

// ---------------------------------------------------------------------------
extern "C" void kernel_launch(void* const* d_in, const int* in_sizes, int n_in,
                              void* d_out, int out_size, void* d_ws, size_t ws_size,
                              hipStream_t stream)
{
    const float* H_l      = (const float*)d_in[0];
    const float* H_a      = (const float*)d_in[1];
    const float* W_text   = (const float*)d_in[2];
    const float* b_text   = (const float*)d_in[3];
    const float* W_audio  = (const float*)d_in[4];
    const float* b_audio  = (const float*)d_in[5];
    const float* W_out    = (const float*)d_in[6];
    const float* b_out    = (const float*)d_in[7];
    const float* g1       = (const float*)d_in[8];
    const float* beta1    = (const float*)d_in[9];
    const float* g2       = (const float*)d_in[10];
    const float* beta2    = (const float*)d_in[11];
    const float* g_out    = (const float*)d_in[12];
    const float* beta_out = (const float*)d_in[13];
    (void)in_sizes; (void)n_in; (void)out_size;

    const int B = 16, L = 1024, S = 2048, DT = 1024, DA = 768, H = 1024;

    // ---------------- workspace layout (~245.5 MiB, heavy overlay) ---------
    char* ws = (char*)d_ws;
    const size_t SZ_HLB = (size_t)B * L * DT * 2;
    const size_t SZ_HAB = (size_t)B * S * DA * 2;
    const size_t O_A    = SZ_HLB + SZ_HAB;
    const size_t SZ_A   = (size_t)B * L * H * 2;
    const size_t O_C    = O_A + SZ_A;
    const size_t SZ_C   = (size_t)B * S * H * 2;
    const size_t O_D    = O_C + SZ_C;
    const size_t SZ_D   = (size_t)B * S * H * 2;
    const size_t O_W    = O_D + SZ_D;
    const size_t need   = O_W + (size_t)(DT * H + DA * H + H * H) * 2;

    if (ws_size < need) {
        fprintf(stderr, "[kernel_launch] ws_size=%zu < needed=%zu — aborting launches\n",
                ws_size, need);
        return;
    }

    u16*   Hlb     = (u16*)(ws);
    u16*   Hab     = (u16*)(ws + SZ_HLB);
    u16*   Scores  = (u16*)(ws);                 // overlays Hlb/Hab after G2
    u16*   Abuf    = (u16*)(ws + O_A);           // text_p -> Q -> Hh
    u16*   Vbuf    = (u16*)(ws + O_C);           // audio_p (LN2 input)
    u16*   Kbuf    = (u16*)(ws + O_D);           // K
    u16*   OutPre  = (u16*)(ws + O_D);           // out_pre bf16 (after K dies)
    u16*   Wt_text  = (u16*)(ws + O_W);
    u16*   Wt_audio = Wt_text + (size_t)DT * H;
    u16*   Wt_out   = Wt_audio + (size_t)DA * H;
    u16*   Vt      = (u16*)d_out;                // dies before final LN

    const float scale = 0.03125f; // 1/sqrt(1024)

    // merged input casts to bf16 (one dispatch)
    const long nHl8 = (long)B * L * DT / 8;      // 2,097,152
    const long nHa8 = (long)B * S * DA / 8;      // 3,145,728
    cast2_f32_bf16<<<(unsigned)((nHl8 + nHa8 + 255) / 256), 256, 0, stream>>>(
        H_l, Hlb, nHl8, H_a, Hab, nHa8);
    // merged weight transposes [K,N] -> [N,K] bf16 (one dispatch)
    tcast3_f32_bf16<<<dim3(H / 32, 32, 3), dim3(32, 8), 0, stream>>>(
        W_text, Wt_text, W_audio, Wt_audio, W_out, Wt_out);

    // G1: text_p = H_l @ W_text + b_text   [16384,1024] bf16
    gemm_nt<1, true, false, true, false><<<dim3(H / 256, B * L / 256, 1), 512, 0, stream>>>(
        Hlb, Wt_text, Abuf, b_text, nullptr, nullptr, DT, DT, DT, H, 0, 0, 0, 1.0f);
    // LN1 in-place: text_p -> Q
    ln1024<true, true><<<B * L, 256, 0, stream>>>(Abuf, g1, beta1, Abuf);

    // G2: audio_p = H_a @ W_audio + b_audio [32768,1024] bf16 (= V),
    //     epilogue also writes V^T into Vt (d_out) -> no transpose kernel
    gemm_nt<2, true, false, true, true><<<dim3(H / 256, B * S / 256, 1), 512, 0, stream>>>(
        Hab, Wt_audio, Vbuf, b_audio, nullptr, Vt, DA, DA, DA, H, 0, 0, 0, 1.0f);
    // LN2: audio_p -> K
    ln1024<true, true><<<B * S, 256, 0, stream>>>(Vbuf, g2, beta2, Kbuf);

    // G3: scores = Q @ K^T * scale          [B,1024,2048] bf16
    gemm_nt<3, false, false, true, false><<<dim3(S / 256, L / 256, B), 512, 0, stream>>>(
        Abuf, Kbuf, Scores, nullptr, nullptr, nullptr, H, H, H, S,
        (long)L * H, (long)S * H, (long)L * S, scale);

    // softmax in-place on bf16 scores -> alpha
    softmax2048_bf16<<<B * L, 256, 0, stream>>>(Scores);

    // G5: H_hyper = alpha @ V (NT vs Vt)    [B,1024,1024] bf16 -> Abuf (Q dead)
    gemm_nt<5, false, false, true, false><<<dim3(H / 256, L / 256, B), 512, 0, stream>>>(
        Scores, Vt, Abuf, nullptr, nullptr, nullptr, S, S, S, H,
        (long)L * S, (long)H * S, (long)L * H, 1.0f);

    // G6: out_pre = H_hyper @ W_out + b_out + H_l  [16384,1024] bf16 (K dead)
    gemm_nt<6, true, true, true, false><<<dim3(H / 256, B * L / 256, 1), 512, 0, stream>>>(
        Abuf, Wt_out, OutPre, b_out, H_l, nullptr, H, H, H, H, 0, 0, 0, 1.0f);

    // LN3 (bf16 in) -> d_out fp32 (Vt dead)
    ln1024<true, false><<<B * L, 256, 0, stream>>>(OutPre, g_out, beta_out, (float*)d_out);
}

// Round 16
// 473.166 us; speedup vs baseline: 1.2577x; 1.0002x over previous
//
#include <hip/hip_runtime.h>
#include <cstdio>

typedef unsigned short u16;
typedef __bf16 bf16x8 __attribute__((ext_vector_type(8)));
typedef float f32x4 __attribute__((ext_vector_type(4)));
typedef unsigned short us4 __attribute__((ext_vector_type(4)));
typedef unsigned short us8 __attribute__((ext_vector_type(8)));

__device__ __forceinline__ u16 f2bf(float f) {
    union { float f; unsigned u; } x; x.f = f;
    unsigned u = x.u + 0x7fffu + ((x.u >> 16) & 1u);   // RNE
    return (u16)(u >> 16);
}
__device__ __forceinline__ float bf2f(u16 u) {
    union { unsigned u; float f; } x; x.u = ((unsigned)u) << 16;
    return x.f;
}

// ---------------------------------------------------------------------------
// NT GEMM: C[M,N] = A[M,K] * B[N,K]^T, bf16 in, fp32 accumulate.
// 256x256 tile, BK=64, 512 threads (8 waves 2Mx4N, 128x64 per wave).
// R15 structure with the pA-half bug FIXED: per-phase half-tile staging and
// derived per-phase counted vmcnt (m196: fine ds_read || G::load || MFMA
// interleave is the lever).
// LDS layout: per operand, 2 bufs x 2 half-slots of 16 KB (slot = (kt&1)*2+h).
// A half h holds global rows m0 + h*128 + [0,128); wave wr reads half wr
// (pA = lA + (d*2+wr)*8192, local rows [0,128)).  [R15 BUG: pA lacked +wr.]
// B half h holds rows n0 + h*128 + [0,128); wave wc reads half wc>>1,
// local base (wc&1)*64.
// Stage order during tile T (2 loads/thread per phase), matching T+1's
// consumption order:
//   p1: reads af0(8)+bfr0(4) ; stage Ah0(T+1) ; BAR ; lgkm0 ; Q00 ; vm(4) ; BAR
//   p2: reads bfr1(4)        ; stage Bh0(T+1) ; BAR ; lgkm0 ; Q01 ; vm(4) ; BAR
//   p3: reads af1(8)         ; stage Bh1(T+1) ; BAR ; lgkm0 ; Q10 ;         BAR
//   p4:                        stage Ah1(T+1) ;               Q11 ; vm(4) ; BAR
// Derived waits (2 loads per half-tile):
//   end p1: outstanding {Bh1(T),Ah1(T),Ah0(T+1)}=6 -> vm(4) lands Bh1(T)
//   end p2: outstanding {Ah1(T),Ah0(T+1),Bh0(T+1)}=6 -> vm(4) lands Ah1(T)
//   end p3: p4 register-only -> no wait
//   end p4: outstanding = T+1's 4 halves = 8 -> vm(4) lands Ah0/Bh0(T+1)
//   tail T=nt-1 (no staging): end p1 -> vm(2), end p2 -> vm(0).
// Each vmcnt sits after the MFMA cluster, before the trailing barrier:
// wait+barrier guarantees the next phase's cross-wave RAW.
// WAR ledger: stage target (buf d^1, half h) was last ds_read in iteration
// T-1 (same buffer), drained by that phase's lgkm0 >= 5 barriers earlier.
// XOR-swizzled rows (phys_koff = koff ^ ((row&7)<<4)); stage pre-swizzles
// the GLOBAL source (both-sides rule). Conflicts = 0 (R12-R14 verified).
// EMIT_VT (G2 only): epilogue additionally writes V^T[b][n][s].
// grid: (N/256, M/256, batch) flattened; nwg % 8 == 0 for the XCD remap.
// ---------------------------------------------------------------------------

#define LDFRAG(base, row, koff) \
  (*(const bf16x8*)((const char*)(base) + (size_t)(row) * 128 + \
                    ((koff) ^ (((row) & 7) << 4))))

#define BAR() do { \
  asm volatile("" ::: "memory"); \
  __builtin_amdgcn_s_barrier(); \
  asm volatile("" ::: "memory"); \
} while (0)

#define LGKM0() asm volatile("s_waitcnt lgkmcnt(0)" ::: "memory")
#define VMC4()  asm volatile("s_waitcnt vmcnt(4)" ::: "memory")
#define VMC2()  asm volatile("s_waitcnt vmcnt(2)" ::: "memory")
#define VMC0()  asm volatile("s_waitcnt vmcnt(0)" ::: "memory")

#define MFMA16(AF, BF, MO, NO) do { \
  __builtin_amdgcn_s_setprio(1); \
  _Pragma("unroll") for (int j = 0; j < 4; ++j) \
    _Pragma("unroll") for (int i = 0; i < 2; ++i) \
      _Pragma("unroll") for (int ks = 0; ks < 2; ++ks) \
        acc[(MO) + j][(NO) + i] = __builtin_amdgcn_mfma_f32_16x16x32_bf16( \
            AF[j][ks], BF[i][ks], acc[(MO) + j][(NO) + i], 0, 0, 0); \
  __builtin_amdgcn_s_setprio(0); \
} while (0)

template<int TAG, bool HAS_BIAS, bool HAS_RESID, bool OUT_BF16, bool EMIT_VT>
__global__ __launch_bounds__(512, 2)
void gemm_nt(const u16* __restrict__ A, const u16* __restrict__ Bm,
             void* __restrict__ Cm, const float* __restrict__ bias,
             const float* __restrict__ resid, u16* __restrict__ vt,
             int K, int lda, int ldb, int ldc,
             long sA, long sB, long sC, float scale)
{
    // 2 buffers x 2 half-slots per operand, 8192 u16 (16 KB) each.
    __shared__ __align__(16) u16 lA[4 * 128 * 64];   // 64 KiB
    __shared__ __align__(16) u16 lB[4 * 128 * 64];   // 64 KiB

    const int tid = threadIdx.x;

    // ---- bijective XCD chunking over the flattened 3D grid (nwg%8==0) ----
    const int gx = gridDim.x, gy = gridDim.y;
    int flat = ((int)blockIdx.z * gy + blockIdx.y) * gx + blockIdx.x;
    const int nwg = gx * gy * (int)gridDim.z;
    const int q = nwg >> 3;
    flat = (flat & 7) * q + (flat >> 3);
    const int bx = flat % gx;
    const int t2 = flat / gx;
    const int by = t2 % gy;
    const long bz = t2 / gy;

    A  += bz * sA;
    Bm += bz * sB;
    const long cbase = bz * sC;
    const int m0 = by * 256;
    const int n0 = bx * 256;

    const int lane = tid & 63;
    const int w  = tid >> 6;                  // wave 0..7
    const int wr = w >> 2, wc = w & 3;        // 2x4 wave grid, 128x64 per wave
    const int fr = lane & 15;                 // A row / B col within fragment
    const int kg = lane >> 4;                 // k-group (0..3)

    // stage one half-tile (128 rows x 64 K = 16 KB) of operand op, half h,
    // K-tile kt, into buf (kt&1) half h. Global source pre-swizzled;
    // LDS dest linear. 2 global_load_lds per thread per call.
    auto stage_half = [&](int kt, int op, int h) {
        const u16* src = op ? Bm : A;
        const int  ld  = op ? ldb : lda;
        const int  bs  = op ? n0 : m0;
        u16* lds = (op ? lB : lA) + (size_t)((kt & 1) * 2 + h) * 8192;
#pragma unroll
        for (int i2 = 0; i2 < 2; ++i2) {
            const int c  = i2 * 512 + tid;            // 16B chunk id, 0..1023
            const int r  = c >> 3;                    // row within half
            const int kb = ((c & 7) * 16) ^ ((r & 7) << 4);   // pre-swizzled k byte
            const u16* g = src + (size_t)(bs + h * 128 + r) * ld + kt * 64 + (kb >> 1);
            __builtin_amdgcn_global_load_lds(
                (const __attribute__((address_space(1))) void*)g,
                (__attribute__((address_space(3))) void*)(lds + (size_t)c * 8), 16, 0, 0);
        }
    };

    f32x4 acc[8][4] = {};

    const int nt = K >> 6;                    // nt >= 12 for all GEMMs here
    // prologue: tile 0's halves in consumption order (Ah0, Bh0, Bh1, Ah1)
    stage_half(0, 0, 0); stage_half(0, 1, 0);
    stage_half(0, 1, 1); stage_half(0, 0, 1);
    VMC4();                                   // Ah0(0), Bh0(0) landed
    BAR();

    const int bRowBase = (wc & 1) * 64;       // B local row base within half

    for (int T = 0; T < nt; ++T) {
        const int d = T & 1;
        const u16* pA = lA + (size_t)(d * 2 + wr) * 8192;       // wave's A half
        const u16* pB = lB + (size_t)(d * 2 + (wc >> 1)) * 8192; // wave's B half
        const bool pre = (T + 1 < nt);

        bf16x8 af0[4][2], af1[4][2], bfr0[2][2], bfr1[2][2];

        // ---- phase 1: read af0 (local rows 0-63) + bfr0 ; stage Ah0(T+1) ; Q00
#pragma unroll
        for (int j = 0; j < 4; ++j)
#pragma unroll
            for (int ks = 0; ks < 2; ++ks)
                af0[j][ks] = LDFRAG(pA, j * 16 + fr, ks * 64 + kg * 16);
#pragma unroll
        for (int i = 0; i < 2; ++i)
#pragma unroll
            for (int ks = 0; ks < 2; ++ks)
                bfr0[i][ks] = LDFRAG(pB, bRowBase + i * 16 + fr, ks * 64 + kg * 16);
        if (pre) stage_half(T + 1, 0, 0);
        BAR();
        LGKM0();
        MFMA16(af0, bfr0, 0, 0);
        if (pre) VMC4(); else VMC2();         // guards p2's Bh1(T) read
        BAR();

        // ---- phase 2: read bfr1 ; stage Bh0(T+1) ; Q01 ----
#pragma unroll
        for (int i = 0; i < 2; ++i)
#pragma unroll
            for (int ks = 0; ks < 2; ++ks)
                bfr1[i][ks] = LDFRAG(pB, bRowBase + 32 + i * 16 + fr, ks * 64 + kg * 16);
        if (pre) stage_half(T + 1, 1, 0);
        BAR();
        LGKM0();
        MFMA16(af0, bfr1, 0, 2);
        if (pre) VMC4(); else VMC0();         // guards p3's Ah1(T) read
        BAR();

        // ---- phase 3: read af1 (local rows 64-127) ; stage Bh1(T+1) ; Q10
#pragma unroll
        for (int j = 0; j < 4; ++j)
#pragma unroll
            for (int ks = 0; ks < 2; ++ks)
                af1[j][ks] = LDFRAG(pA, 64 + j * 16 + fr, ks * 64 + kg * 16);
        if (pre) stage_half(T + 1, 1, 1);
        BAR();
        LGKM0();
        MFMA16(af1, bfr0, 4, 0);
        BAR();                                // p4 is register-only: no vmcnt

        // ---- phase 4: stage Ah1(T+1) ; Q11 (register-only MFMA) ----
        if (pre) stage_half(T + 1, 0, 1);
        MFMA16(af1, bfr1, 4, 2);
        if (pre) VMC4();                      // guards next p1's Ah0/Bh0 reads
        BAR();
    }

    // epilogue: C/D layout col=lane&15, row=(lane>>4)*4+reg  [m89-verified]
    const int orow = m0 + wr * 128 + kg * 4;
    const int ocol = n0 + wc * 64 + fr;
#pragma unroll
    for (int mf = 0; mf < 8; ++mf) {
        const int mbase = orow + mf * 16;     // 4 consecutive rows mbase..+3
#pragma unroll
        for (int nf = 0; nf < 4; ++nf) {
            const int n = ocol + nf * 16;
            float v4[4];
#pragma unroll
            for (int r = 0; r < 4; ++r) {
                const int m = mbase + r;
                float v = acc[mf][nf][r] * scale;
                if (HAS_BIAS)  v += bias[n];
                if (HAS_RESID) v += resid[cbase + (long)m * ldc + n];
                v4[r] = v;
                if (OUT_BF16)  ((u16*)Cm)[cbase + (long)m * ldc + n] = f2bf(v);
                else           ((float*)Cm)[cbase + (long)m * ldc + n] = v;
            }
            if (EMIT_VT) {
                // rows m = b*2048 + s; write Vt[b][n][s..s+3] (batch S=2048)
                const long b_ = mbase >> 11;
                const int  s  = mbase & 2047;
                us4 o;
#pragma unroll
                for (int r = 0; r < 4; ++r) o[r] = f2bf(v4[r]);
                *(us4*)(vt + (b_ * 1024 + n) * 2048 + s) = o;
            }
        }
    }
}

// ---------------------------------------------------------------------------
// LayerNorm over D=1024, one block (256 thr) per row.
// ---------------------------------------------------------------------------
template<bool IN_BF16, bool OUT_BF16>
__global__ __launch_bounds__(256)
void ln1024(const void* in, const float* __restrict__ g,
            const float* __restrict__ beta, void* out)
{
    const long row = blockIdx.x;
    const int tid = threadIdx.x;
    float x0, x1, x2, x3;
    if (IN_BF16) {
        const us4 v = ((const us4*)in)[row * 256 + tid];
        x0 = bf2f(v[0]); x1 = bf2f(v[1]); x2 = bf2f(v[2]); x3 = bf2f(v[3]);
    } else {
        const float4 v = ((const float4*)in)[row * 256 + tid];
        x0 = v.x; x1 = v.y; x2 = v.z; x3 = v.w;
    }
    float s  = x0 + x1 + x2 + x3;
    float s2 = x0 * x0 + x1 * x1 + x2 * x2 + x3 * x3;
#pragma unroll
    for (int off = 32; off > 0; off >>= 1) {
        s  += __shfl_xor(s, off);
        s2 += __shfl_xor(s2, off);
    }
    __shared__ float rs[4], rq[4];
    if ((tid & 63) == 0) { rs[tid >> 6] = s; rq[tid >> 6] = s2; }
    __syncthreads();
    const float S  = rs[0] + rs[1] + rs[2] + rs[3];
    const float S2 = rq[0] + rq[1] + rq[2] + rq[3];
    const float mu = S * (1.0f / 1024.0f);
    const float var = S2 * (1.0f / 1024.0f) - mu * mu;
    const float rstd = rsqrtf(var + 1e-5f);
    const float4 gg = ((const float4*)g)[tid];
    const float4 bb = ((const float4*)beta)[tid];
    const float y0 = (x0 - mu) * rstd * gg.x + bb.x;
    const float y1 = (x1 - mu) * rstd * gg.y + bb.y;
    const float y2 = (x2 - mu) * rstd * gg.z + bb.z;
    const float y3 = (x3 - mu) * rstd * gg.w + bb.w;
    if (OUT_BF16) {
        us4 o; o[0] = f2bf(y0); o[1] = f2bf(y1); o[2] = f2bf(y2); o[3] = f2bf(y3);
        ((us4*)out)[row * 256 + tid] = o;
    } else {
        float4 o; o.x = y0; o.y = y1; o.z = y2; o.w = y3;
        ((float4*)out)[row * 256 + tid] = o;
    }
}

// ---------------------------------------------------------------------------
// Softmax over width 2048, bf16 in/out, IN-PLACE. One block per row.
// ---------------------------------------------------------------------------
__global__ __launch_bounds__(256)
void softmax2048_bf16(u16* io)
{
    const long row = blockIdx.x;
    const int tid = threadIdx.x;
    const us8 v = ((const us8*)io)[row * 256 + tid];
    float x[8];
#pragma unroll
    for (int i = 0; i < 8; ++i) x[i] = bf2f(v[i]);
    float m = x[0];
#pragma unroll
    for (int i = 1; i < 8; ++i) m = fmaxf(m, x[i]);
#pragma unroll
    for (int off = 32; off > 0; off >>= 1) m = fmaxf(m, __shfl_xor(m, off));
    __shared__ float rm[4], rsum[4];
    if ((tid & 63) == 0) rm[tid >> 6] = m;
    __syncthreads();
    m = fmaxf(fmaxf(rm[0], rm[1]), fmaxf(rm[2], rm[3]));
    float e[8];
    float s = 0.f;
#pragma unroll
    for (int i = 0; i < 8; ++i) { e[i] = __expf(x[i] - m); s += e[i]; }
#pragma unroll
    for (int off = 32; off > 0; off >>= 1) s += __shfl_xor(s, off);
    if ((tid & 63) == 0) rsum[tid >> 6] = s;
    __syncthreads();
    s = rsum[0] + rsum[1] + rsum[2] + rsum[3];
    const float inv = 1.0f / s;
    us8 o;
#pragma unroll
    for (int i = 0; i < 8; ++i) o[i] = f2bf(e[i] * inv);
    ((us8*)io)[row * 256 + tid] = o;
}

// ---------------------------------------------------------------------------
// Merged input cast: fp32 -> bf16, 8 elems/thread, two sources in one grid.
// ---------------------------------------------------------------------------
__global__ __launch_bounds__(256)
void cast2_f32_bf16(const float* __restrict__ srcA, u16* __restrict__ dstA, long nA8,
                    const float* __restrict__ srcB, u16* __restrict__ dstB, long nB8)
{
    long i = (long)blockIdx.x * 256 + threadIdx.x;
    const float* in;
    u16* out;
    if (i < nA8) { in = srcA; out = dstA; }
    else         { i -= nA8; if (i >= nB8) return; in = srcB; out = dstB; }
    const float4 a = ((const float4*)in)[i * 2];
    const float4 b = ((const float4*)in)[i * 2 + 1];
    us8 o;
    o[0] = f2bf(a.x); o[1] = f2bf(a.y); o[2] = f2bf(a.z); o[3] = f2bf(a.w);
    o[4] = f2bf(b.x); o[5] = f2bf(b.y); o[6] = f2bf(b.z); o[7] = f2bf(b.w);
    ((us8*)out)[i] = o;
}

// ---------------------------------------------------------------------------
// Merged weight transpose+cast: fp32 [R,C] -> bf16 [C,R], 3 weights in one
// grid (z selects descriptor; row-guard for z==1 R=768). block (32,8).
// ---------------------------------------------------------------------------
__global__ __launch_bounds__(256)
void tcast3_f32_bf16(const float* __restrict__ w0, u16* __restrict__ t0,
                     const float* __restrict__ w1, u16* __restrict__ t1,
                     const float* __restrict__ w2, u16* __restrict__ t2)
{
    const int z = blockIdx.z;
    const float* in; u16* out; int R;
    if      (z == 0) { in = w0; out = t0; R = 1024; }
    else if (z == 1) { in = w1; out = t1; R = 768;  }
    else             { in = w2; out = t2; R = 1024; }
    const int C = 1024;
    const int r0 = blockIdx.y * 32;
    if (r0 >= R) return;
    __shared__ float t[32][33];
    const int tx = threadIdx.x, ty = threadIdx.y;
    const int c0 = blockIdx.x * 32;
#pragma unroll
    for (int i = 0; i < 4; ++i)
        t[ty + i * 8][tx] = in[(long)(r0 + ty + i * 8) * C + c0 + tx];
    __syncthreads();
#pragma unroll
    for (int i = 0; i < 4; ++i)
        out[(long)(c0 + ty + i * 8) * R + r0 + tx] = f2bf(t[tx][ty + i * 8]);
}

// ---------------------------------------------------------------------------
extern "C" void kernel_launch(void* const* d_in, const int* in_sizes, int n_in,
                              void* d_out, int out_size, void* d_ws, size_t ws_size,
                              hipStream_t stream)
{
    const float* H_l      = (const float*)d_in[0];
    const float* H_a      = (const float*)d_in[1];
    const float* W_text   = (const float*)d_in[2];
    const float* b_text   = (const float*)d_in[3];
    const float* W_audio  = (const float*)d_in[4];
    const float* b_audio  = (const float*)d_in[5];
    const float* W_out    = (const float*)d_in[6];
    const float* b_out    = (const float*)d_in[7];
    const float* g1       = (const float*)d_in[8];
    const float* beta1    = (const float*)d_in[9];
    const float* g2       = (const float*)d_in[10];
    const float* beta2    = (const float*)d_in[11];
    const float* g_out    = (const float*)d_in[12];
    const float* beta_out = (const float*)d_in[13];
    (void)in_sizes; (void)n_in; (void)out_size;

    const int B = 16, L = 1024, S = 2048, DT = 1024, DA = 768, H = 1024;

    // ---------------- workspace layout (~245.5 MiB, heavy overlay) ---------
    char* ws = (char*)d_ws;
    const size_t SZ_HLB = (size_t)B * L * DT * 2;
    const size_t SZ_HAB = (size_t)B * S * DA * 2;
    const size_t O_A    = SZ_HLB + SZ_HAB;
    const size_t SZ_A   = (size_t)B * L * H * 2;
    const size_t O_C    = O_A + SZ_A;
    const size_t SZ_C   = (size_t)B * S * H * 2;
    const size_t O_D    = O_C + SZ_C;
    const size_t SZ_D   = (size_t)B * S * H * 2;
    const size_t O_W    = O_D + SZ_D;
    const size_t need   = O_W + (size_t)(DT * H + DA * H + H * H) * 2;

    if (ws_size < need) {
        fprintf(stderr, "[kernel_launch] ws_size=%zu < needed=%zu — aborting launches\n",
                ws_size, need);
        return;
    }

    u16*   Hlb     = (u16*)(ws);
    u16*   Hab     = (u16*)(ws + SZ_HLB);
    u16*   Scores  = (u16*)(ws);                 // overlays Hlb/Hab after G2
    u16*   Abuf    = (u16*)(ws + O_A);           // text_p -> Q -> Hh
    u16*   Vbuf    = (u16*)(ws + O_C);           // audio_p (LN2 input)
    u16*   Kbuf    = (u16*)(ws + O_D);           // K
    u16*   OutPre  = (u16*)(ws + O_D);           // out_pre bf16 (after K dies)
    u16*   Wt_text  = (u16*)(ws + O_W);
    u16*   Wt_audio = Wt_text + (size_t)DT * H;
    u16*   Wt_out   = Wt_audio + (size_t)DA * H;
    u16*   Vt      = (u16*)d_out;                // dies before final LN

    const float scale = 0.03125f; // 1/sqrt(1024)

    // merged input casts to bf16 (one dispatch)
    const long nHl8 = (long)B * L * DT / 8;
    const long nHa8 = (long)B * S * DA / 8;
    cast2_f32_bf16<<<(unsigned)((nHl8 + nHa8 + 255) / 256), 256, 0, stream>>>(
        H_l, Hlb, nHl8, H_a, Hab, nHa8);
    // merged weight transposes [K,N] -> [N,K] bf16 (one dispatch)
    tcast3_f32_bf16<<<dim3(H / 32, 32, 3), dim3(32, 8), 0, stream>>>(
        W_text, Wt_text, W_audio, Wt_audio, W_out, Wt_out);

    // G1: text_p = H_l @ W_text + b_text   [16384,1024] bf16
    gemm_nt<1, true, false, true, false><<<dim3(H / 256, B * L / 256, 1), 512, 0, stream>>>(
        Hlb, Wt_text, Abuf, b_text, nullptr, nullptr, DT, DT, DT, H, 0, 0, 0, 1.0f);
    // LN1 in-place: text_p -> Q
    ln1024<true, true><<<B * L, 256, 0, stream>>>(Abuf, g1, beta1, Abuf);

    // G2: audio_p = H_a @ W_audio + b_audio [32768,1024] bf16 (= V),
    //     epilogue also writes V^T into Vt (d_out) -> no transpose kernel
    gemm_nt<2, true, false, true, true><<<dim3(H / 256, B * S / 256, 1), 512, 0, stream>>>(
        Hab, Wt_audio, Vbuf, b_audio, nullptr, Vt, DA, DA, DA, H, 0, 0, 0, 1.0f);
    // LN2: audio_p -> K
    ln1024<true, true><<<B * S, 256, 0, stream>>>(Vbuf, g2, beta2, Kbuf);

    // G3: scores = Q @ K^T * scale          [B,1024,2048] bf16
    gemm_nt<3, false, false, true, false><<<dim3(S / 256, L / 256, B), 512, 0, stream>>>(
        Abuf, Kbuf, Scores, nullptr, nullptr, nullptr, H, H, H, S,
        (long)L * H, (long)S * H, (long)L * S, scale);

    // softmax in-place on bf16 scores -> alpha
    softmax2048_bf16<<<B * L, 256, 0, stream>>>(Scores);

    // G5: H_hyper = alpha @ V (NT vs Vt)    [B,1024,1024] bf16 -> Abuf (Q dead)
    gemm_nt<5, false, false, true, false><<<dim3(H / 256, L / 256, B), 512, 0, stream>>>(
        Scores, Vt, Abuf, nullptr, nullptr, nullptr, S, S, S, H,
        (long)L * S, (long)H * S, (long)L * H, 1.0f);

    // G6: out_pre = H_hyper @ W_out + b_out + H_l  [16384,1024] bf16 (K dead)
    gemm_nt<6, true, true, true, false><<<dim3(H / 256, B * L / 256, 1), 512, 0, stream>>>(
        Abuf, Wt_out, OutPre, b_out, H_l, nullptr, H, H, H, H, 0, 0, 0, 1.0f);

    // LN3 (bf16 in) -> d_out fp32 (Vt dead)
    ln1024<true, false><<<B * L, 256, 0, stream>>>(OutPre, g_out, beta_out, (float*)d_out);
}